// Round 1
// baseline (25840.744 us; speedup 1.0000x reference)
//
#include <hip/hip_runtime.h>

typedef unsigned short u16;
typedef unsigned int   u32;
typedef unsigned long long u64;
typedef __attribute__((ext_vector_type(8))) short short8;   // 8 x bf16 operand (4 VGPRs)
typedef __attribute__((ext_vector_type(4))) float f32x4;    // MFMA accumulator

// ---------------- workspace layout (bytes) ----------------
// G1   : [16384 rows (t*32+b)][4096 gate-rows] bf16  = 134217728
// h1buf: 2 parity buffers, A-fragment layout, 65536 B each
// h2buf: same
// h2f  : final h2 [32][1024] fp32
// cnt  : 8 padded barrier counters
#define OFF_H1   134217728ull
#define OFF_H2   (OFF_H1 + 131072ull)
#define OFF_H2F  (OFF_H2 + 131072ull)
#define OFF_CNT  (OFF_H2F + 131072ull)

__device__ inline u16 f2bf(float f) {                  // fp32 -> bf16 RNE
  u32 x = __float_as_uint(f);
  x += 0x7fffu + ((x >> 16) & 1u);
  return (u16)(x >> 16);
}
__device__ inline float bf2f(u16 u) { return __uint_as_float(((u32)u) << 16); }

__device__ inline short8 pack_bf16x8(float4 a, float4 b) {
  short8 r;
  r[0] = (short)f2bf(a.x); r[1] = (short)f2bf(a.y); r[2] = (short)f2bf(a.z); r[3] = (short)f2bf(a.w);
  r[4] = (short)f2bf(b.x); r[5] = (short)f2bf(b.y); r[6] = (short)f2bf(b.z); r[7] = (short)f2bf(b.w);
  return r;
}

struct U64x2 { u64 lo, hi; };
__device__ inline short8 frag_cast(u64 lo, u64 hi) {
  U64x2 t{lo, hi};
  return __builtin_bit_cast(short8, t);
}

__device__ inline float sigf(float x) { return 1.f / (1.f + __expf(-x)); }
__device__ inline float tanhfast(float x) {
  x = fminf(15.f, fmaxf(-15.f, x));
  float e = __expf(2.f * x);
  return (e - 1.f) / (e + 1.f);
}

// ---------------- init: zero h double-buffers + barrier counters ----------------
__global__ void init_zero_k(uint4* __restrict__ z, int n4, u32* __restrict__ cnt) {
  const int i = blockIdx.x * blockDim.x + threadIdx.x;
  if (i < n4)  z[i] = make_uint4(0u, 0u, 0u, 0u);
  if (i < 256) cnt[i] = 0u;
}

// ---------------- phase A: G1[n][r] = emb[x] @ Wih1^T (bf16 MFMA) ----------------
// n = t*32 + b (A-row), r = gate-row 0..4095. 128x128 tile, BK=64, gather fused into A-stage.
__global__ __launch_bounds__(256) void gemm_g1(
    const int* __restrict__ x, const float* __restrict__ emb,
    const float* __restrict__ Wih, u16* __restrict__ G1)
{
  __shared__ __align__(16) u16 lA[128 * 72];   // +8 bf16 row pad: dword stride 36 = 4 mod 32
  __shared__ __align__(16) u16 lB[128 * 72];
  __shared__ int tokoff[128];

  const int tid = threadIdx.x;
  const int ntb = blockIdx.x & 31;     // N tile (gate rows)
  const int mtb = blockIdx.x >> 5;     // M tile (time*batch rows); consecutive blocks share A rows

  if (tid < 128) {
    const int n = mtb * 128 + tid;
    tokoff[tid] = x[(n & 31) * 512 + (n >> 5)];   // x[b][t], b=n&31, t=n>>5
  }
  __syncthreads();

  const int lane = tid & 63;
  const int wv = tid >> 6;
  const int wm = (wv & 1) * 64;
  const int wn = (wv >> 1) * 64;

  const f32x4 zero = {0.f, 0.f, 0.f, 0.f};
  f32x4 acc[4][4];
#pragma unroll
  for (int i = 0; i < 4; ++i)
#pragma unroll
    for (int j = 0; j < 4; ++j) acc[i][j] = zero;

  const int rowS = tid >> 1;
  const int kh = (tid & 1) * 32;
  const size_t embrow = (size_t)tokoff[rowS] * 1024;
  const size_t wihrow = (size_t)(ntb * 128 + rowS) * 1024;

  for (int kk = 0; kk < 1024; kk += 64) {
    __syncthreads();
    {
      const float4* sa = (const float4*)(emb + embrow + kk + kh);
      const float4* sb = (const float4*)(Wih + wihrow + kk + kh);
#pragma unroll
      for (int v = 0; v < 4; ++v) {
        *(short8*)&lA[rowS * 72 + kh + v * 8] = pack_bf16x8(sa[2 * v], sa[2 * v + 1]);
        *(short8*)&lB[rowS * 72 + kh + v * 8] = pack_bf16x8(sb[2 * v], sb[2 * v + 1]);
      }
    }
    __syncthreads();
#pragma unroll
    for (int ks = 0; ks < 2; ++ks) {
      short8 aF[4], bF[4];
#pragma unroll
      for (int i = 0; i < 4; ++i)
        aF[i] = *(const short8*)&lA[(wm + i * 16 + (lane & 15)) * 72 + ks * 32 + (lane >> 4) * 8];
#pragma unroll
      for (int i = 0; i < 4; ++i)
        bF[i] = *(const short8*)&lB[(wn + i * 16 + (lane & 15)) * 72 + ks * 32 + (lane >> 4) * 8];
#pragma unroll
      for (int i = 0; i < 4; ++i)
#pragma unroll
        for (int j = 0; j < 4; ++j)
          acc[i][j] = __builtin_amdgcn_mfma_f32_16x16x32_bf16(aF[i], bF[j], acc[i][j], 0, 0, 0);
    }
  }

  const int rb = mtb * 128 + wm + (lane >> 4) * 4;   // D row = A row (m)
  const int cb = ntb * 128 + wn + (lane & 15);       // D col = gate row (n)
#pragma unroll
  for (int i = 0; i < 4; ++i)
#pragma unroll
    for (int j = 0; j < 4; ++j)
#pragma unroll
      for (int r = 0; r < 4; ++r)
        G1[(size_t)(rb + i * 16 + r) * 4096 + cb + j * 16] = f2bf(acc[i][j][r]);
}

// ---------------- grid barrier: 8 padded counters, wave-parallel poll ----------------
__device__ inline void gbar(u32* cnt, u32 target) {
  __syncthreads();
  if (threadIdx.x == 0)
    __hip_atomic_fetch_add(cnt + ((blockIdx.x & 7) << 4), 1u,
                           __ATOMIC_RELEASE, __HIP_MEMORY_SCOPE_AGENT);
  if (threadIdx.x < 64) {
    int guard = 0;
    for (;;) {
      unsigned v = 0;
      if (threadIdx.x < 8)
        v = __hip_atomic_load(cnt + (threadIdx.x << 4),
                              __ATOMIC_ACQUIRE, __HIP_MEMORY_SCOPE_AGENT);
      v += __shfl_xor(v, 1);
      v += __shfl_xor(v, 2);
      v += __shfl_xor(v, 4);
      v = __shfl(v, 0);
      if (v >= target) break;
      if (++guard > (1 << 20)) break;   // hang insurance (fails validation, not the run)
      __builtin_amdgcn_s_sleep(1);
    }
  }
  __syncthreads();
  __builtin_amdgcn_fence(__ATOMIC_ACQUIRE, "agent");  // invalidate stale L1/L2 before plain h loads
}

// ---------------- persistent fused 2-layer LSTM recurrence ----------------
// 256 blocks (1/CU). Blocks 0..127: layer 1 (8 hidden units each, Whh1 frags VGPR-resident).
// Blocks 128..255: layer 2 (Wih2 + Whh2 frags VGPR-resident), lagging one sweep step.
// h exchanged via global double-buffers stored in MFMA A-fragment layout:
//   chunk(mt,ks,lane) = ((mt*32+ks)*64+lane), 16 B per chunk; value h[b][k] at
//   mt=b>>4, ks=k>>5, lane=((k&31)>>3)<<4 | (b&15), byte 2*(k&7).
__global__ __launch_bounds__(256, 1) void lstm_recur(
    const float* __restrict__ Wih_all, const float* __restrict__ Whh_all,
    const float* __restrict__ bias_all, const u16* __restrict__ G1,
    u64* __restrict__ h1buf, u64* __restrict__ h2buf,
    float* __restrict__ h2f, u32* __restrict__ cnt)
{
  __shared__ float gatesLds[32 * 33];            // [b][col], padded
  __shared__ __align__(16) u16 hpack[32 * 8];    // [b][u] bf16 staging for frag store

  const int tid = threadIdx.x;
  const int lane = tid & 63;
  const int wv = tid >> 6;
  const int mt = wv & 1;        // batch 16-tile
  const int nt = wv >> 1;       // gate-col 16-tile
  const int bid = blockIdx.x;
  const int layer = bid >> 7;
  const int w = bid & 127;      // owns hidden units j = w*8 .. w*8+7

  const int pu = tid & 7;       // pointwise: unit
  const int pb = tid >> 3;      // pointwise: batch
  float creg = 0.f;             // cell state lives in a register
  float bs0, bs1, bs2, bs3;
  {
    const float* bb = bias_all + layer * 4096 + w * 8 + pu;
    bs0 = bb[0]; bs1 = bb[1024]; bs2 = bb[2048]; bs3 = bb[3072];
  }

  // --- one-time: load weight B-fragments into VGPRs (fp32 -> bf16) ---
  // wave's col n = nt*16 + (lane&15); col order within WG: [i(8),f(8),g(8),o(8)] -> W row gate*1024 + w*8 + u
  short8 bw0[32];   // layer0: Whh1 ; layer1: Wih2
  short8 bw1[32];   // layer1: Whh2
  {
    const int c = lane & 15, q = lane >> 4;
    const int n = nt * 16 + c;
    const size_t wrow = (size_t)((n >> 3) * 1024 + w * 8 + (n & 7)) * 1024;
    const float* src0 = (layer == 0) ? (Whh_all + wrow) : (Wih_all + 4194304 + wrow);
#pragma unroll
    for (int ks = 0; ks < 32; ++ks) {
      const float4* p = (const float4*)(src0 + ks * 32 + q * 8);
      bw0[ks] = pack_bf16x8(p[0], p[1]);
    }
    if (layer == 1) {
      const float* src1 = Whh_all + 4194304 + wrow;
#pragma unroll
      for (int ks = 0; ks < 32; ++ks) {
        const float4* p = (const float4*)(src1 + ks * 32 + q * 8);
        bw1[ks] = pack_bf16x8(p[0], p[1]);
      }
    }
  }

  for (int s = 0; s < 513; ++s) {
    const bool active = (layer == 0) ? (s < 512) : (s >= 1);
    f32x4 acc = {0.f, 0.f, 0.f, 0.f};
    float g0 = 0.f, g1v = 0.f, g2 = 0.f, g3 = 0.f;
    if (active) {
      if (layer == 0) {
        // prefetch precomputed input-projection gates (issued early, consumed after MFMAs)
        const u16* gp = G1 + (size_t)(s * 32 + pb) * 4096 + w * 8 + pu;
        g0 = bf2f(gp[0]); g1v = bf2f(gp[1024]); g2 = bf2f(gp[2048]); g3 = bf2f(gp[3072]);
        const u64* hb = h1buf + (size_t)((s - 1) & 1) * 8192;
#pragma unroll
        for (int ks = 0; ks < 32; ++ks) {
          const u64* p = hb + (size_t)(((mt * 32 + ks) * 64 + lane) * 2);
          acc = __builtin_amdgcn_mfma_f32_16x16x32_bf16(frag_cast(p[0], p[1]), bw0[ks], acc, 0, 0, 0);
        }
      } else {
        const int t2 = s - 1;
        const u64* hbA = h1buf + (size_t)(t2 & 1) * 8192;        // h1[t2]
        const u64* hbB = h2buf + (size_t)((t2 - 1) & 1) * 8192;  // h2[t2-1]
#pragma unroll
        for (int ks = 0; ks < 32; ++ks) {
          const u64* p = hbA + (size_t)(((mt * 32 + ks) * 64 + lane) * 2);
          acc = __builtin_amdgcn_mfma_f32_16x16x32_bf16(frag_cast(p[0], p[1]), bw0[ks], acc, 0, 0, 0);
        }
#pragma unroll
        for (int ks = 0; ks < 32; ++ks) {
          const u64* p = hbB + (size_t)(((mt * 32 + ks) * 64 + lane) * 2);
          acc = __builtin_amdgcn_mfma_f32_16x16x32_bf16(frag_cast(p[0], p[1]), bw1[ks], acc, 0, 0, 0);
        }
      }
      // C/D layout: row (batch) = (lane>>4)*4+reg, col = lane&15  [m89/m91 orientation]
#pragma unroll
      for (int r = 0; r < 4; ++r)
        gatesLds[(mt * 16 + (lane >> 4) * 4 + r) * 33 + nt * 16 + (lane & 15)] = acc[r];
    }
    __syncthreads();
    if (active) {
      const float* gl = gatesLds + pb * 33;
      float gi = gl[pu]       + bs0 + g0;
      float gf = gl[8 + pu]   + bs1 + g1v;
      float gg = gl[16 + pu]  + bs2 + g2;
      float go = gl[24 + pu]  + bs3 + g3;
      creg = sigf(gf) * creg + sigf(gi) * tanhfast(gg);
      const float hval = sigf(go) * tanhfast(creg);
      hpack[pb * 8 + pu] = f2bf(hval);
      if (layer == 1 && s == 512) h2f[pb * 1024 + w * 8 + pu] = hval;
    }
    __syncthreads();
    if (active && tid < 32) {
      const int b = tid;
      const u64* hp = (const u64*)(hpack + b * 8);
      const u64 lo = hp[0], hi = hp[1];
      u64* dst = (layer == 0) ? (h1buf + (size_t)(s & 1) * 8192)
                              : (h2buf + (size_t)((s - 1) & 1) * 8192);
      // WG w's units j=w*8+u: ks=w>>2, lane=((w&3)<<4)|(b&15), bytes u*2 within chunk
      const int chunk = ((b >> 4) * 32 + (w >> 2)) * 64 + ((w & 3) << 4) + (b & 15);
      // agent-scope stores: land at the coherence point (cross-XCD visible, no bulk L2 flush)
      __hip_atomic_store(dst + chunk * 2,     lo, __ATOMIC_RELAXED, __HIP_MEMORY_SCOPE_AGENT);
      __hip_atomic_store(dst + chunk * 2 + 1, hi, __ATOMIC_RELAXED, __HIP_MEMORY_SCOPE_AGENT);
    }
    if (s < 512) gbar(cnt, (u32)(256u * (u32)(s + 1)));
  }
}

// ---------------- epilogue: logits, log-softmax, NLL ----------------
__global__ __launch_bounds__(256) void epilogue_k(
    const float* __restrict__ h2f, const float* __restrict__ fcW,
    const float* __restrict__ fcb, const int* __restrict__ labels,
    float* __restrict__ out)
{
  __shared__ float slog[160];
  __shared__ float snll[32];
  const int tid = threadIdx.x;
  const int lane = tid & 63;
  const int wv = tid >> 6;
  for (int d = wv * 40; d < (wv + 1) * 40; ++d) {
    const int b = d / 5, l = d - b * 5;
    const float* hr = h2f + b * 1024 + lane * 16;
    const float* wr = fcW + l * 1024 + lane * 16;
    float sacc = 0.f;
#pragma unroll
    for (int i = 0; i < 16; ++i) sacc += hr[i] * wr[i];
#pragma unroll
    for (int off = 32; off > 0; off >>= 1) sacc += __shfl_down(sacc, off);
    if (lane == 0) slog[d] = sacc + fcb[l];
  }
  __syncthreads();
  if (tid < 32) {
    const int b = tid;
    float m = slog[b * 5];
    for (int l = 1; l < 5; ++l) m = fmaxf(m, slog[b * 5 + l]);
    float se = 0.f;
    for (int l = 0; l < 5; ++l) se += __expf(slog[b * 5 + l] - m);
    const float lse = m + __logf(se);
    for (int l = 0; l < 5; ++l) out[1 + b * 5 + l] = slog[b * 5 + l];
    snll[b] = lse - slog[b * 5 + labels[b]];
  }
  __syncthreads();
  if (tid == 0) {
    float a = 0.f;
    for (int b = 0; b < 32; ++b) a += snll[b];
    out[0] = a * (1.f / 32.f);
  }
}

extern "C" void kernel_launch(void* const* d_in, const int* in_sizes, int n_in,
                              void* d_out, int out_size, void* d_ws, size_t ws_size,
                              hipStream_t stream)
{
  const int*   x      = (const int*)  d_in[0];
  const int*   labels = (const int*)  d_in[1];
  const float* emb    = (const float*)d_in[2];
  const float* W_ih   = (const float*)d_in[3];
  const float* W_hh   = (const float*)d_in[4];
  const float* bias   = (const float*)d_in[5];
  const float* fcW    = (const float*)d_in[6];
  const float* fcb    = (const float*)d_in[7];
  float* out = (float*)d_out;

  char* ws = (char*)d_ws;
  u16* G1    = (u16*)ws;
  u64* h1buf = (u64*)(ws + OFF_H1);
  u64* h2buf = (u64*)(ws + OFF_H2);
  float* h2f = (float*)(ws + OFF_H2F);
  u32* cnt   = (u32*)(ws + OFF_CNT);

  // zero h double-buffers (262144 B = 16384 uint4) + barrier counters
  init_zero_k<<<dim3(64), dim3(256), 0, stream>>>((uint4*)(ws + OFF_H1), 16384, cnt);
  // phase A: all input projections for layer 1
  gemm_g1<<<dim3(4096), dim3(256), 0, stream>>>(x, emb, W_ih, G1);
  // persistent fused recurrence (1 block per CU; capacity argument guarantees residency)
  lstm_recur<<<dim3(256), dim3(256), 0, stream>>>(W_ih, W_hh, bias, G1, h1buf, h2buf, h2f, cnt);
  // loss + logits
  epilogue_k<<<dim3(1), dim3(256), 0, stream>>>(h2f, fcW, fcb, labels, out);
}

// Round 2
// 10261.352 us; speedup vs baseline: 2.5183x; 2.5183x over previous
//
#include <hip/hip_runtime.h>

typedef unsigned short u16;
typedef unsigned int   u32;
typedef unsigned long long u64;
typedef __attribute__((ext_vector_type(8))) short short8;   // 8 x bf16 operand (4 VGPRs)
typedef __attribute__((ext_vector_type(4))) float f32x4;    // MFMA accumulator

// ---------------- workspace layout (bytes) ----------------
// G1   : [16384 rows (t*32+b)][4096 gate-rows] bf16  = 134217728
// h1buf: 2 parity buffers, A-fragment layout, 65536 B each
// h2buf: same
// h2f  : final h2 [32][1024] fp32
// cnt  : 8 barrier counters, 128-B padded
#define OFF_H1   134217728ull
#define OFF_H2   (OFF_H1 + 131072ull)
#define OFF_H2F  (OFF_H2 + 131072ull)
#define OFF_CNT  (OFF_H2F + 131072ull)

__device__ inline u16 f2bf(float f) {                  // fp32 -> bf16 RNE
  u32 x = __float_as_uint(f);
  x += 0x7fffu + ((x >> 16) & 1u);
  return (u16)(x >> 16);
}
__device__ inline float bf2f(u16 u) { return __uint_as_float(((u32)u) << 16); }

__device__ inline short8 pack_bf16x8(float4 a, float4 b) {
  short8 r;
  r[0] = (short)f2bf(a.x); r[1] = (short)f2bf(a.y); r[2] = (short)f2bf(a.z); r[3] = (short)f2bf(a.w);
  r[4] = (short)f2bf(b.x); r[5] = (short)f2bf(b.y); r[6] = (short)f2bf(b.z); r[7] = (short)f2bf(b.w);
  return r;
}

struct U64x2 { u64 lo, hi; };
__device__ inline short8 frag_cast(u64 lo, u64 hi) {
  U64x2 t{lo, hi};
  return __builtin_bit_cast(short8, t);
}

// agent-scope, per-access coherent load of one 16-B A-fragment (no cache-wide inv needed)
__device__ inline short8 load_frag_agent(const u64* p) {
  u64 lo = __hip_atomic_load(p,     __ATOMIC_RELAXED, __HIP_MEMORY_SCOPE_AGENT);
  u64 hi = __hip_atomic_load(p + 1, __ATOMIC_RELAXED, __HIP_MEMORY_SCOPE_AGENT);
  return frag_cast(lo, hi);
}

__device__ inline float sigf(float x) { return 1.f / (1.f + __expf(-x)); }
__device__ inline float tanhfast(float x) {
  x = fminf(15.f, fmaxf(-15.f, x));
  float e = __expf(2.f * x);
  return (e - 1.f) / (e + 1.f);
}

// ---------------- init: zero h double-buffers + barrier counters ----------------
__global__ void init_zero_k(uint4* __restrict__ z, int n4, u32* __restrict__ cnt) {
  const int i = blockIdx.x * blockDim.x + threadIdx.x;
  if (i < n4)  z[i] = make_uint4(0u, 0u, 0u, 0u);
  if (i < 256) cnt[i] = 0u;
}

// ---------------- phase A: G1[n][r] = emb[x] @ Wih1^T (bf16 MFMA) ----------------
__global__ __launch_bounds__(256) void gemm_g1(
    const int* __restrict__ x, const float* __restrict__ emb,
    const float* __restrict__ Wih, u16* __restrict__ G1)
{
  __shared__ __align__(16) u16 lA[128 * 72];   // +8 bf16 row pad
  __shared__ __align__(16) u16 lB[128 * 72];
  __shared__ int tokoff[128];

  const int tid = threadIdx.x;
  const int ntb = blockIdx.x & 31;     // N tile (gate rows)
  const int mtb = blockIdx.x >> 5;     // M tile (time*batch rows)

  if (tid < 128) {
    const int n = mtb * 128 + tid;
    tokoff[tid] = x[(n & 31) * 512 + (n >> 5)];   // x[b][t], b=n&31, t=n>>5
  }
  __syncthreads();

  const int lane = tid & 63;
  const int wv = tid >> 6;
  const int wm = (wv & 1) * 64;
  const int wn = (wv >> 1) * 64;

  const f32x4 zero = {0.f, 0.f, 0.f, 0.f};
  f32x4 acc[4][4];
#pragma unroll
  for (int i = 0; i < 4; ++i)
#pragma unroll
    for (int j = 0; j < 4; ++j) acc[i][j] = zero;

  const int rowS = tid >> 1;
  const int kh = (tid & 1) * 32;
  const size_t embrow = (size_t)tokoff[rowS] * 1024;
  const size_t wihrow = (size_t)(ntb * 128 + rowS) * 1024;

  for (int kk = 0; kk < 1024; kk += 64) {
    __syncthreads();
    {
      const float4* sa = (const float4*)(emb + embrow + kk + kh);
      const float4* sb = (const float4*)(Wih + wihrow + kk + kh);
#pragma unroll
      for (int v = 0; v < 4; ++v) {
        *(short8*)&lA[rowS * 72 + kh + v * 8] = pack_bf16x8(sa[2 * v], sa[2 * v + 1]);
        *(short8*)&lB[rowS * 72 + kh + v * 8] = pack_bf16x8(sb[2 * v], sb[2 * v + 1]);
      }
    }
    __syncthreads();
#pragma unroll
    for (int ks = 0; ks < 2; ++ks) {
      short8 aF[4], bF[4];
#pragma unroll
      for (int i = 0; i < 4; ++i)
        aF[i] = *(const short8*)&lA[(wm + i * 16 + (lane & 15)) * 72 + ks * 32 + (lane >> 4) * 8];
#pragma unroll
      for (int i = 0; i < 4; ++i)
        bF[i] = *(const short8*)&lB[(wn + i * 16 + (lane & 15)) * 72 + ks * 32 + (lane >> 4) * 8];
#pragma unroll
      for (int i = 0; i < 4; ++i)
#pragma unroll
        for (int j = 0; j < 4; ++j)
          acc[i][j] = __builtin_amdgcn_mfma_f32_16x16x32_bf16(aF[i], bF[j], acc[i][j], 0, 0, 0);
    }
  }

  const int rb = mtb * 128 + wm + (lane >> 4) * 4;   // D row = A row (m)
  const int cb = ntb * 128 + wn + (lane & 15);       // D col = gate row (n)
#pragma unroll
  for (int i = 0; i < 4; ++i)
#pragma unroll
    for (int j = 0; j < 4; ++j)
#pragma unroll
      for (int r = 0; r < 4; ++r)
        G1[(size_t)(rb + i * 16 + r) * 4096 + cb + j * 16] = f2bf(acc[i][j][r]);
}

// ---------------- grid barrier: ALL RELAXED (no buffer_wbl2 / buffer_inv) ----------------
// Ordering contract: caller's wave 0 has already drained its h stores (s_waitcnt 0)
// before thread 0 posts. Consumers read h with agent-scope atomic loads (cache-
// bypassing), so no acquire fence / cache invalidate is needed.
__device__ inline void gbar(u32* cnt, u32 target) {
  asm volatile("" ::: "memory");
  if (threadIdx.x == 0)
    __hip_atomic_fetch_add(cnt + ((blockIdx.x & 7) << 5), 1u,
                           __ATOMIC_RELAXED, __HIP_MEMORY_SCOPE_AGENT);
  if (threadIdx.x < 64) {
    int guard = 0;
    for (;;) {
      u32 v = 0;
      if (threadIdx.x < 8)
        v = __hip_atomic_load(cnt + (threadIdx.x << 5),
                              __ATOMIC_RELAXED, __HIP_MEMORY_SCOPE_AGENT);
      v += __shfl_xor(v, 1);
      v += __shfl_xor(v, 2);
      v += __shfl_xor(v, 4);
      v = __shfl(v, 0);
      if (v >= target) break;
      if (++guard > (1 << 20)) break;   // hang insurance
      __builtin_amdgcn_s_sleep(1);
    }
  }
  __syncthreads();
  asm volatile("" ::: "memory");
}

// ---------------- persistent fused 2-layer LSTM recurrence ----------------
__global__ __launch_bounds__(256, 1) void lstm_recur(
    const float* __restrict__ Wih_all, const float* __restrict__ Whh_all,
    const float* __restrict__ bias_all, const u16* __restrict__ G1,
    u64* __restrict__ h1buf, u64* __restrict__ h2buf,
    float* __restrict__ h2f, u32* __restrict__ cnt)
{
  __shared__ float gatesLds[32 * 33];            // [b][col], padded
  __shared__ __align__(16) u16 hpack[32 * 8];    // [b][u] bf16 staging for frag store

  const int tid = threadIdx.x;
  const int lane = tid & 63;
  const int wv = tid >> 6;
  const int mt = wv & 1;        // batch 16-tile
  const int nt = wv >> 1;       // gate-col 16-tile
  const int bid = blockIdx.x;
  const int layer = bid >> 7;
  const int w = bid & 127;      // owns hidden units j = w*8 .. w*8+7

  const int pu = tid & 7;       // pointwise: unit
  const int pb = tid >> 3;      // pointwise: batch
  float creg = 0.f;             // cell state lives in a register
  float bs0, bs1, bs2, bs3;
  {
    const float* bb = bias_all + layer * 4096 + w * 8 + pu;
    bs0 = bb[0]; bs1 = bb[1024]; bs2 = bb[2048]; bs3 = bb[3072];
  }

  // --- one-time: load weight B-fragments into VGPRs (fp32 -> bf16) ---
  short8 bw0[32];   // layer0: Whh1 ; layer1: Wih2
  short8 bw1[32];   // layer1: Whh2
  {
    const int c = lane & 15, q = lane >> 4;
    const int n = nt * 16 + c;
    const size_t wrow = (size_t)((n >> 3) * 1024 + w * 8 + (n & 7)) * 1024;
    const float* src0 = (layer == 0) ? (Whh_all + wrow) : (Wih_all + 4194304 + wrow);
#pragma unroll
    for (int ks = 0; ks < 32; ++ks) {
      const float4* p = (const float4*)(src0 + ks * 32 + q * 8);
      bw0[ks] = pack_bf16x8(p[0], p[1]);
    }
    if (layer == 1) {
      const float* src1 = Whh_all + 4194304 + wrow;
#pragma unroll
      for (int ks = 0; ks < 32; ++ks) {
        const float4* p = (const float4*)(src1 + ks * 32 + q * 8);
        bw1[ks] = pack_bf16x8(p[0], p[1]);
      }
    }
  }

  // prefetch step-0 input-projection gates (layer 0)
  float g0 = 0.f, g1v = 0.f, g2 = 0.f, g3 = 0.f;
  if (layer == 0) {
    const u16* gp = G1 + (size_t)pb * 4096 + w * 8 + pu;
    g0 = bf2f(gp[0]); g1v = bf2f(gp[1024]); g2 = bf2f(gp[2048]); g3 = bf2f(gp[3072]);
  }

  for (int s = 0; s < 513; ++s) {
    const bool active = (layer == 0) ? (s < 512) : (s >= 1);
    f32x4 acc = {0.f, 0.f, 0.f, 0.f};
    if (active) {
      if (layer == 0) {
        const u64* hb = h1buf + (size_t)((s - 1) & 1) * 8192;
#pragma unroll
        for (int ks = 0; ks < 32; ++ks) {
          const u64* p = hb + (size_t)(((mt * 32 + ks) * 64 + lane) * 2);
          acc = __builtin_amdgcn_mfma_f32_16x16x32_bf16(load_frag_agent(p), bw0[ks], acc, 0, 0, 0);
        }
      } else {
        const int t2 = s - 1;
        const u64* hbA = h1buf + (size_t)(t2 & 1) * 8192;        // h1[t2]
        const u64* hbB = h2buf + (size_t)((t2 - 1) & 1) * 8192;  // h2[t2-1]
#pragma unroll
        for (int ks = 0; ks < 32; ++ks) {
          const u64* p = hbA + (size_t)(((mt * 32 + ks) * 64 + lane) * 2);
          acc = __builtin_amdgcn_mfma_f32_16x16x32_bf16(load_frag_agent(p), bw0[ks], acc, 0, 0, 0);
        }
#pragma unroll
        for (int ks = 0; ks < 32; ++ks) {
          const u64* p = hbB + (size_t)(((mt * 32 + ks) * 64 + lane) * 2);
          acc = __builtin_amdgcn_mfma_f32_16x16x32_bf16(load_frag_agent(p), bw1[ks], acc, 0, 0, 0);
        }
      }
      // C/D layout: row (batch) = (lane>>4)*4+reg, col = lane&15
#pragma unroll
      for (int r = 0; r < 4; ++r)
        gatesLds[(mt * 16 + (lane >> 4) * 4 + r) * 33 + nt * 16 + (lane & 15)] = acc[r];
    }
    __syncthreads();
    if (active) {
      const float* gl = gatesLds + pb * 33;
      float gi = gl[pu]       + bs0 + g0;
      float gf = gl[8 + pu]   + bs1 + g1v;
      float gg = gl[16 + pu]  + bs2 + g2;
      float go = gl[24 + pu]  + bs3 + g3;
      creg = sigf(gf) * creg + sigf(gi) * tanhfast(gg);
      const float hval = sigf(go) * tanhfast(creg);
      hpack[pb * 8 + pu] = f2bf(hval);
      if (layer == 1 && s == 512) h2f[pb * 1024 + w * 8 + pu] = hval;
    }
    __syncthreads();
    if (active && tid < 32) {
      const int b = tid;
      const u64* hp = (const u64*)(hpack + b * 8);
      const u64 lo = hp[0], hi = hp[1];
      u64* dst = (layer == 0) ? (h1buf + (size_t)(s & 1) * 8192)
                              : (h2buf + (size_t)((s - 1) & 1) * 8192);
      const int chunk = ((b >> 4) * 32 + (w >> 2)) * 64 + ((w & 3) << 4) + (b & 15);
      __hip_atomic_store(dst + chunk * 2,     lo, __ATOMIC_RELAXED, __HIP_MEMORY_SCOPE_AGENT);
      __hip_atomic_store(dst + chunk * 2 + 1, hi, __ATOMIC_RELAXED, __HIP_MEMORY_SCOPE_AGENT);
    }
    // prefetch next step's G1 gates (layer 0) — overlaps the barrier poll
    if (layer == 0 && s + 1 < 512) {
      const u16* gp = G1 + (size_t)((s + 1) * 32 + pb) * 4096 + w * 8 + pu;
      g0 = bf2f(gp[0]); g1v = bf2f(gp[1024]); g2 = bf2f(gp[2048]); g3 = bf2f(gp[3072]);
    }
    if (s < 512) {
      // wave 0 drains its h stores before thread 0 posts (ordering w/o release fence)
      if (wv == 0) __builtin_amdgcn_s_waitcnt(0);
      gbar(cnt, (u32)(256u * (u32)(s + 1)));
    }
  }
}

// ---------------- epilogue: logits, log-softmax, NLL ----------------
__global__ __launch_bounds__(256) void epilogue_k(
    const float* __restrict__ h2f, const float* __restrict__ fcW,
    const float* __restrict__ fcb, const int* __restrict__ labels,
    float* __restrict__ out)
{
  __shared__ float slog[160];
  __shared__ float snll[32];
  const int tid = threadIdx.x;
  const int lane = tid & 63;
  const int wv = tid >> 6;
  for (int d = wv * 40; d < (wv + 1) * 40; ++d) {
    const int b = d / 5, l = d - b * 5;
    const float* hr = h2f + b * 1024 + lane * 16;
    const float* wr = fcW + l * 1024 + lane * 16;
    float sacc = 0.f;
#pragma unroll
    for (int i = 0; i < 16; ++i) sacc += hr[i] * wr[i];
#pragma unroll
    for (int off = 32; off > 0; off >>= 1) sacc += __shfl_down(sacc, off);
    if (lane == 0) slog[d] = sacc + fcb[l];
  }
  __syncthreads();
  if (tid < 32) {
    const int b = tid;
    float m = slog[b * 5];
    for (int l = 1; l < 5; ++l) m = fmaxf(m, slog[b * 5 + l]);
    float se = 0.f;
    for (int l = 0; l < 5; ++l) se += __expf(slog[b * 5 + l] - m);
    const float lse = m + __logf(se);
    for (int l = 0; l < 5; ++l) out[1 + b * 5 + l] = slog[b * 5 + l];
    snll[b] = lse - slog[b * 5 + labels[b]];
  }
  __syncthreads();
  if (tid == 0) {
    float a = 0.f;
    for (int b = 0; b < 32; ++b) a += snll[b];
    out[0] = a * (1.f / 32.f);
  }
}

extern "C" void kernel_launch(void* const* d_in, const int* in_sizes, int n_in,
                              void* d_out, int out_size, void* d_ws, size_t ws_size,
                              hipStream_t stream)
{
  const int*   x      = (const int*)  d_in[0];
  const int*   labels = (const int*)  d_in[1];
  const float* emb    = (const float*)d_in[2];
  const float* W_ih   = (const float*)d_in[3];
  const float* W_hh   = (const float*)d_in[4];
  const float* bias   = (const float*)d_in[5];
  const float* fcW    = (const float*)d_in[6];
  const float* fcb    = (const float*)d_in[7];
  float* out = (float*)d_out;

  char* ws = (char*)d_ws;
  u16* G1    = (u16*)ws;
  u64* h1buf = (u64*)(ws + OFF_H1);
  u64* h2buf = (u64*)(ws + OFF_H2);
  float* h2f = (float*)(ws + OFF_H2F);
  u32* cnt   = (u32*)(ws + OFF_CNT);

  // zero h double-buffers (262144 B = 16384 uint4) + barrier counters
  init_zero_k<<<dim3(64), dim3(256), 0, stream>>>((uint4*)(ws + OFF_H1), 16384, cnt);
  // phase A: all input projections for layer 1
  gemm_g1<<<dim3(4096), dim3(256), 0, stream>>>(x, emb, W_ih, G1);
  // persistent fused recurrence (1 block per CU)
  lstm_recur<<<dim3(256), dim3(256), 0, stream>>>(W_ih, W_hh, bias, G1, h1buf, h2buf, h2f, cnt);
  // loss + logits
  epilogue_k<<<dim3(1), dim3(256), 0, stream>>>(h2f, fcW, fcb, labels, out);
}

// Round 3
// 5291.650 us; speedup vs baseline: 4.8833x; 1.9392x over previous
//
#include <hip/hip_runtime.h>

typedef unsigned short u16;
typedef unsigned int   u32;
typedef unsigned long long u64;
typedef __attribute__((ext_vector_type(8))) short short8;    // 8 x bf16 operand (4 VGPRs)
typedef __attribute__((ext_vector_type(4))) float f32x4;     // 16x16 MFMA accumulator
typedef __attribute__((ext_vector_type(16))) float f32x16;   // 32x32 MFMA accumulator

// ---------------- workspace layout (bytes) ----------------
// G1   : [16384 rows (t*32+b)][4096 gate-rows] bf16  = 134217728
// h1buf: 2 parity buffers, 32x32-A-fragment layout (chunk = kb*32 + b, 16 B), 64 KiB each
// h2buf: same
// h2f  : final h2 [32][1024] fp32
// cnt  : 8 barrier counters, 128-B padded
#define OFF_H1   134217728ull
#define OFF_H2   (OFF_H1 + 131072ull)
#define OFF_H2F  (OFF_H2 + 131072ull)
#define OFF_CNT  (OFF_H2F + 131072ull)

__device__ inline u16 f2bf(float f) {                  // fp32 -> bf16 RNE
  u32 x = __float_as_uint(f);
  x += 0x7fffu + ((x >> 16) & 1u);
  return (u16)(x >> 16);
}
__device__ inline float bf2f(u16 u) { return __uint_as_float(((u32)u) << 16); }

__device__ inline short8 pack_bf16x8(float4 a, float4 b) {
  short8 r;
  r[0] = (short)f2bf(a.x); r[1] = (short)f2bf(a.y); r[2] = (short)f2bf(a.z); r[3] = (short)f2bf(a.w);
  r[4] = (short)f2bf(b.x); r[5] = (short)f2bf(b.y); r[6] = (short)f2bf(b.z); r[7] = (short)f2bf(b.w);
  return r;
}

struct U64x2 { u64 lo, hi; };
__device__ inline short8 frag_cast(u64 lo, u64 hi) {
  U64x2 t{lo, hi};
  return __builtin_bit_cast(short8, t);
}

// agent-scope, per-access coherent load of one 16-B A-fragment (no cache-wide inv needed)
__device__ inline short8 load_frag_agent(const u64* p) {
  u64 lo = __hip_atomic_load(p,     __ATOMIC_RELAXED, __HIP_MEMORY_SCOPE_AGENT);
  u64 hi = __hip_atomic_load(p + 1, __ATOMIC_RELAXED, __HIP_MEMORY_SCOPE_AGENT);
  return frag_cast(lo, hi);
}

__device__ inline f32x16 mfma32(short8 a, short8 b, f32x16 c) {
  return __builtin_amdgcn_mfma_f32_32x32x16_bf16(a, b, c, 0, 0, 0);
}

__device__ inline float sigf(float x) { return 1.f / (1.f + __expf(-x)); }
__device__ inline float tanhfast(float x) {
  x = fminf(15.f, fmaxf(-15.f, x));
  float e = __expf(2.f * x);
  return (e - 1.f) / (e + 1.f);
}

// ---------------- init: zero h double-buffers + barrier counters ----------------
__global__ void init_zero_k(uint4* __restrict__ z, int n4, u32* __restrict__ cnt) {
  const int i = blockIdx.x * blockDim.x + threadIdx.x;
  if (i < n4)  z[i] = make_uint4(0u, 0u, 0u, 0u);
  if (i < 256) cnt[i] = 0u;
}

// ---------------- phase A: G1[n][r] = emb[x] @ Wih1^T (bf16 MFMA) ----------------
__global__ __launch_bounds__(256) void gemm_g1(
    const int* __restrict__ x, const float* __restrict__ emb,
    const float* __restrict__ Wih, u16* __restrict__ G1)
{
  __shared__ __align__(16) u16 lA[128 * 72];   // +8 bf16 row pad
  __shared__ __align__(16) u16 lB[128 * 72];
  __shared__ int tokoff[128];

  const int tid = threadIdx.x;
  const int ntb = blockIdx.x & 31;     // N tile (gate rows)
  const int mtb = blockIdx.x >> 5;     // M tile (time*batch rows)

  if (tid < 128) {
    const int n = mtb * 128 + tid;
    tokoff[tid] = x[(n & 31) * 512 + (n >> 5)];   // x[b][t], b=n&31, t=n>>5
  }
  __syncthreads();

  const int lane = tid & 63;
  const int wv = tid >> 6;
  const int wm = (wv & 1) * 64;
  const int wn = (wv >> 1) * 64;

  const f32x4 zero = {0.f, 0.f, 0.f, 0.f};
  f32x4 acc[4][4];
#pragma unroll
  for (int i = 0; i < 4; ++i)
#pragma unroll
    for (int j = 0; j < 4; ++j) acc[i][j] = zero;

  const int rowS = tid >> 1;
  const int kh = (tid & 1) * 32;
  const size_t embrow = (size_t)tokoff[rowS] * 1024;
  const size_t wihrow = (size_t)(ntb * 128 + rowS) * 1024;

  for (int kk = 0; kk < 1024; kk += 64) {
    __syncthreads();
    {
      const float4* sa = (const float4*)(emb + embrow + kk + kh);
      const float4* sb = (const float4*)(Wih + wihrow + kk + kh);
#pragma unroll
      for (int v = 0; v < 4; ++v) {
        *(short8*)&lA[rowS * 72 + kh + v * 8] = pack_bf16x8(sa[2 * v], sa[2 * v + 1]);
        *(short8*)&lB[rowS * 72 + kh + v * 8] = pack_bf16x8(sb[2 * v], sb[2 * v + 1]);
      }
    }
    __syncthreads();
#pragma unroll
    for (int ks = 0; ks < 2; ++ks) {
      short8 aF[4], bF[4];
#pragma unroll
      for (int i = 0; i < 4; ++i)
        aF[i] = *(const short8*)&lA[(wm + i * 16 + (lane & 15)) * 72 + ks * 32 + (lane >> 4) * 8];
#pragma unroll
      for (int i = 0; i < 4; ++i)
        bF[i] = *(const short8*)&lB[(wn + i * 16 + (lane & 15)) * 72 + ks * 32 + (lane >> 4) * 8];
#pragma unroll
      for (int i = 0; i < 4; ++i)
#pragma unroll
        for (int j = 0; j < 4; ++j)
          acc[i][j] = __builtin_amdgcn_mfma_f32_16x16x32_bf16(aF[i], bF[j], acc[i][j], 0, 0, 0);
    }
  }

  const int rb = mtb * 128 + wm + (lane >> 4) * 4;   // D row = A row (m)
  const int cb = ntb * 128 + wn + (lane & 15);       // D col = gate row (n)
#pragma unroll
  for (int i = 0; i < 4; ++i)
#pragma unroll
    for (int j = 0; j < 4; ++j)
#pragma unroll
      for (int r = 0; r < 4; ++r)
        G1[(size_t)(rb + i * 16 + r) * 4096 + cb + j * 16] = f2bf(acc[i][j][r]);
}

// ---------------- grid barrier: ALL RELAXED (no buffer_wbl2 / buffer_inv) ----------------
__device__ inline void gbar(u32* cnt, u32 target) {
  asm volatile("" ::: "memory");
  if (threadIdx.x == 0)
    __hip_atomic_fetch_add(cnt + ((blockIdx.x & 7) << 5), 1u,
                           __ATOMIC_RELAXED, __HIP_MEMORY_SCOPE_AGENT);
  if (threadIdx.x < 64) {
    int guard = 0;
    for (;;) {
      u32 v = 0;
      if (threadIdx.x < 8)
        v = __hip_atomic_load(cnt + (threadIdx.x << 5),
                              __ATOMIC_RELAXED, __HIP_MEMORY_SCOPE_AGENT);
      v += __shfl_xor(v, 1);
      v += __shfl_xor(v, 2);
      v += __shfl_xor(v, 4);
      v = __shfl(v, 0);
      if (v >= target) break;
      if (++guard > (1 << 20)) break;   // hang insurance
      __builtin_amdgcn_s_sleep(1);
    }
  }
  __syncthreads();
  asm volatile("" ::: "memory");
}

// ---------------- persistent fused 2-layer LSTM recurrence (32x32 MFMA, K split over waves) ----
// 256 blocks (1/CU). Block w of a layer owns hidden units w*8..w*8+7 (= h-chunk kb=w).
// Wave split: L0: wave wv does K in [wv*256, wv*256+256) of Whh1 (16 frags = 64 VGPRs).
//             L1: waves 0,1 = K-halves of Wih2 (A=h1[t2]); waves 2,3 = K-halves of Whh2
//                 (A=h2[t2-1]) (32 frags = 128 VGPRs).
// Partial 32x32 gate tiles summed via LDS in the pointwise phase.
// h buffers: 32x32 A-frag layout: chunk(kb,b) = kb*32+b holds h[b][kb*8 .. kb*8+7] bf16.
__global__ __launch_bounds__(256, 1) void lstm_recur(
    const float* __restrict__ Wih_all, const float* __restrict__ Whh_all,
    const float* __restrict__ bias_all, const u16* __restrict__ G1,
    u64* __restrict__ h1buf, u64* __restrict__ h2buf,
    float* __restrict__ h2f, u32* __restrict__ cnt)
{
  __shared__ float gp[4][32][33];                // per-wave partial gates (16.9 KB)
  __shared__ __align__(16) u16 hpack[32 * 8];    // [b][u] bf16 staging for chunk store

  const int tid = threadIdx.x;
  const int lane = tid & 63;
  const int wv = tid >> 6;
  const int bid = blockIdx.x;
  const int layer = bid >> 7;
  const int w = bid & 127;      // owns hidden units j = w*8 .. w*8+7

  const int pu = tid & 7;       // pointwise: unit
  const int pb = tid >> 3;      // pointwise: batch
  float creg = 0.f;             // cell state lives in a register
  float bs0, bs1, bs2, bs3;
  {
    const float* bb = bias_all + layer * 4096 + w * 8 + pu;
    bs0 = bb[0]; bs1 = bb[1024]; bs2 = bb[2048]; bs3 = bb[3072];
  }

  // ---- per-wave GEMM slice & weight B-fragments (VGPR-resident, no spill) ----
  const int K0w = (layer == 0) ? (wv * 256) : ((wv & 1) * 512);
  const int nA = lane & 31;                  // gate col within block
  const int kpart = (lane >> 5) * 8;         // k sub-offset inside a 16-k MFMA step
  const size_t wrow = (size_t)((nA >> 3) * 1024 + w * 8 + (nA & 7)) * 1024;
  const float* Wsrc = (layer == 0) ? Whh_all
                    : ((wv < 2) ? (Wih_all + 4194304) : (Whh_all + 4194304));

  short8 bw[32];   // L0 uses [0..16), L1 uses all 32
#pragma unroll
  for (int ks = 0; ks < 16; ++ks) {
    const float* p = Wsrc + wrow + (K0w + ks * 16 + kpart);
    bw[ks] = pack_bf16x8(((const float4*)p)[0], ((const float4*)p)[1]);
  }
  if (layer == 1) {
#pragma unroll
    for (int ks = 16; ks < 32; ++ks) {
      const float* p = Wsrc + wrow + (K0w + ks * 16 + kpart);
      bw[ks] = pack_bf16x8(((const float4*)p)[0], ((const float4*)p)[1]);
    }
  }

  // A-frag address constant: chunk = ((K0w>>3) + ks*2 + (lane>>5))*32 + (lane&31)
  const int cA = (((K0w >> 3) + (lane >> 5)) * 32 + (lane & 31)) * 2;   // u64 index

  // prefetch step-0 input-projection gates (layer 0)
  float g0 = 0.f, g1v = 0.f, g2 = 0.f, g3 = 0.f;
  if (layer == 0) {
    const u16* gpt = G1 + (size_t)pb * 4096 + w * 8 + pu;
    g0 = bf2f(gpt[0]); g1v = bf2f(gpt[1024]); g2 = bf2f(gpt[2048]); g3 = bf2f(gpt[3072]);
  }

  for (int s = 0; s <= 512; ++s) {
    const bool active = (layer == 0) ? (s < 512) : (s >= 1);
    if (active) {
      const u64* hb;
      if (layer == 0) {
        hb = h1buf + (size_t)((s - 1) & 1) * 8192;
      } else {
        const int t2 = s - 1;
        hb = (wv < 2) ? (h1buf + (size_t)(t2 & 1) * 8192)
                      : (h2buf + (size_t)((t2 - 1) & 1) * 8192);
      }
      const u64* bp = hb + cA;
      f32x16 acc = {0.f,0.f,0.f,0.f,0.f,0.f,0.f,0.f,0.f,0.f,0.f,0.f,0.f,0.f,0.f,0.f};
      short8 a0[8], a1[8];
#pragma unroll
      for (int f = 0; f < 8; ++f) a0[f] = load_frag_agent(bp + 128 * f);
#pragma unroll
      for (int f = 0; f < 8; ++f) a1[f] = load_frag_agent(bp + 128 * (8 + f));
      if (layer == 0) {
#pragma unroll
        for (int f = 0; f < 8; ++f) acc = mfma32(a0[f], bw[f], acc);
#pragma unroll
        for (int f = 0; f < 8; ++f) acc = mfma32(a1[f], bw[8 + f], acc);
      } else {
#pragma unroll
        for (int f = 0; f < 8; ++f) acc = mfma32(a0[f], bw[f], acc);
#pragma unroll
        for (int f = 0; f < 8; ++f) a0[f] = load_frag_agent(bp + 128 * (16 + f));
#pragma unroll
        for (int f = 0; f < 8; ++f) acc = mfma32(a1[f], bw[8 + f], acc);
#pragma unroll
        for (int f = 0; f < 8; ++f) a1[f] = load_frag_agent(bp + 128 * (24 + f));
#pragma unroll
        for (int f = 0; f < 8; ++f) acc = mfma32(a0[f], bw[16 + f], acc);
#pragma unroll
        for (int f = 0; f < 8; ++f) acc = mfma32(a1[f], bw[24 + f], acc);
      }
      // 32x32 C/D layout: col = lane&31, row = (reg&3) + 8*(reg>>2) + 4*(lane>>5)
#pragma unroll
      for (int r = 0; r < 16; ++r)
        gp[wv][(r & 3) + 8 * (r >> 2) + 4 * (lane >> 5)][lane & 31] = acc[r];
    }
    __syncthreads();
    if (active) {
      float gi = bs0 + g0, gf = bs1 + g1v, gg = bs2 + g2, go = bs3 + g3;
#pragma unroll
      for (int q = 0; q < 4; ++q) {
        gi += gp[q][pb][pu];
        gf += gp[q][pb][8 + pu];
        gg += gp[q][pb][16 + pu];
        go += gp[q][pb][24 + pu];
      }
      creg = sigf(gf) * creg + sigf(gi) * tanhfast(gg);
      const float hval = sigf(go) * tanhfast(creg);
      hpack[pb * 8 + pu] = f2bf(hval);
      if (layer == 1 && s == 512) h2f[pb * 1024 + w * 8 + pu] = hval;
    }
    __syncthreads();
    if (active && tid < 32) {
      const u64* hp = (const u64*)(hpack + tid * 8);
      const u64 lo = hp[0], hi = hp[1];
      u64* dst = (layer == 0) ? (h1buf + (size_t)(s & 1) * 8192)
                              : (h2buf + (size_t)((s - 1) & 1) * 8192);
      const int chunk = w * 32 + tid;           // chunk(kb=w, b=tid)
      __hip_atomic_store(dst + chunk * 2,     lo, __ATOMIC_RELAXED, __HIP_MEMORY_SCOPE_AGENT);
      __hip_atomic_store(dst + chunk * 2 + 1, hi, __ATOMIC_RELAXED, __HIP_MEMORY_SCOPE_AGENT);
    }
    // prefetch next step's G1 gates (layer 0) — overlaps the barrier poll
    if (layer == 0 && s + 1 < 512) {
      const u16* gpt = G1 + (size_t)((s + 1) * 32 + pb) * 4096 + w * 8 + pu;
      g0 = bf2f(gpt[0]); g1v = bf2f(gpt[1024]); g2 = bf2f(gpt[2048]); g3 = bf2f(gpt[3072]);
    }
    if (s < 512) {
      // wave 0 drains its h stores before thread 0 posts (ordering w/o release fence)
      if (wv == 0) __builtin_amdgcn_s_waitcnt(0);
      gbar(cnt, (u32)(256u * (u32)(s + 1)));
    }
  }
}

// ---------------- epilogue: logits, log-softmax, NLL ----------------
__global__ __launch_bounds__(256) void epilogue_k(
    const float* __restrict__ h2f, const float* __restrict__ fcW,
    const float* __restrict__ fcb, const int* __restrict__ labels,
    float* __restrict__ out)
{
  __shared__ float slog[160];
  __shared__ float snll[32];
  const int tid = threadIdx.x;
  const int lane = tid & 63;
  const int wv = tid >> 6;
  for (int d = wv * 40; d < (wv + 1) * 40; ++d) {
    const int b = d / 5, l = d - b * 5;
    const float* hr = h2f + b * 1024 + lane * 16;
    const float* wr = fcW + l * 1024 + lane * 16;
    float sacc = 0.f;
#pragma unroll
    for (int i = 0; i < 16; ++i) sacc += hr[i] * wr[i];
#pragma unroll
    for (int off = 32; off > 0; off >>= 1) sacc += __shfl_down(sacc, off);
    if (lane == 0) slog[d] = sacc + fcb[l];
  }
  __syncthreads();
  if (tid < 32) {
    const int b = tid;
    float m = slog[b * 5];
    for (int l = 1; l < 5; ++l) m = fmaxf(m, slog[b * 5 + l]);
    float se = 0.f;
    for (int l = 0; l < 5; ++l) se += __expf(slog[b * 5 + l] - m);
    const float lse = m + __logf(se);
    for (int l = 0; l < 5; ++l) out[1 + b * 5 + l] = slog[b * 5 + l];
    snll[b] = lse - slog[b * 5 + labels[b]];
  }
  __syncthreads();
  if (tid == 0) {
    float a = 0.f;
    for (int b = 0; b < 32; ++b) a += snll[b];
    out[0] = a * (1.f / 32.f);
  }
}

extern "C" void kernel_launch(void* const* d_in, const int* in_sizes, int n_in,
                              void* d_out, int out_size, void* d_ws, size_t ws_size,
                              hipStream_t stream)
{
  const int*   x      = (const int*)  d_in[0];
  const int*   labels = (const int*)  d_in[1];
  const float* emb    = (const float*)d_in[2];
  const float* W_ih   = (const float*)d_in[3];
  const float* W_hh   = (const float*)d_in[4];
  const float* bias   = (const float*)d_in[5];
  const float* fcW    = (const float*)d_in[6];
  const float* fcb    = (const float*)d_in[7];
  float* out = (float*)d_out;

  char* ws = (char*)d_ws;
  u16* G1    = (u16*)ws;
  u64* h1buf = (u64*)(ws + OFF_H1);
  u64* h2buf = (u64*)(ws + OFF_H2);
  float* h2f = (float*)(ws + OFF_H2F);
  u32* cnt   = (u32*)(ws + OFF_CNT);

  // zero h double-buffers (262144 B = 16384 uint4) + barrier counters
  init_zero_k<<<dim3(64), dim3(256), 0, stream>>>((uint4*)(ws + OFF_H1), 16384, cnt);
  // phase A: all input projections for layer 1
  gemm_g1<<<dim3(4096), dim3(256), 0, stream>>>(x, emb, W_ih, G1);
  // persistent fused recurrence (1 block per CU)
  lstm_recur<<<dim3(256), dim3(256), 0, stream>>>(W_ih, W_hh, bias, G1, h1buf, h2buf, h2f, cnt);
  // loss + logits
  epilogue_k<<<dim3(1), dim3(256), 0, stream>>>(h2f, fcW, fcb, labels, out);
}

// Round 6
// 3902.777 us; speedup vs baseline: 6.6211x; 1.3559x over previous
//
#include <hip/hip_runtime.h>

typedef unsigned short u16;
typedef unsigned int   u32;
typedef unsigned long long u64;
typedef __attribute__((ext_vector_type(8))) short short8;    // 8 x bf16 operand (4 VGPRs)
typedef __attribute__((ext_vector_type(4))) float f32x4;     // 16x16 MFMA accumulator
typedef __attribute__((ext_vector_type(16))) float f32x16;   // 32x32 MFMA accumulator

// ---------------- workspace layout (bytes) ----------------
// G1   : [512 t][128 w][4 gate][8 u][32 b] bf16 = 134217728  (block-local 2 KB slabs)
// h1buf: 2 parity buffers, 32x32-A-fragment layout (chunk = kb*32 + b, 16 B), 64 KiB each
// h2buf: same
// h2f  : final h2 [32][1024] fp32
// cnt  : 8 barrier counters, 128-B padded (within proven 1 KiB region)
#define OFF_H1   134217728ull
#define OFF_H2   (OFF_H1 + 131072ull)
#define OFF_H2F  (OFF_H2 + 131072ull)
#define OFF_CNT  (OFF_H2F + 131072ull)

__device__ inline u16 f2bf(float f) {                  // fp32 -> bf16 RNE
  u32 x = __float_as_uint(f);
  x += 0x7fffu + ((x >> 16) & 1u);
  return (u16)(x >> 16);
}
__device__ inline float bf2f(u16 u) { return __uint_as_float(((u32)u) << 16); }

__device__ inline short8 pack_bf16x8(float4 a, float4 b) {
  short8 r;
  r[0] = (short)f2bf(a.x); r[1] = (short)f2bf(a.y); r[2] = (short)f2bf(a.z); r[3] = (short)f2bf(a.w);
  r[4] = (short)f2bf(b.x); r[5] = (short)f2bf(b.y); r[6] = (short)f2bf(b.z); r[7] = (short)f2bf(b.w);
  return r;
}

__device__ inline f32x16 mfma32(short8 a, short8 b, f32x16 c) {
  return __builtin_amdgcn_mfma_f32_32x32x16_bf16(a, b, c, 0, 0, 0);
}

__device__ inline float sigf(float x) { return 1.f / (1.f + __expf(-x)); }
__device__ inline float tanhfast(float x) {
  x = fminf(15.f, fmaxf(-15.f, x));
  float e = __expf(2.f * x);
  return (e - 1.f) / (e + 1.f);
}

// 16 coherent (LLC-direct) 16-B loads at +1024-B stride, fully pipelined.
// ALL outputs early-clobber ("=&v"): they must NOT alias the address inputs,
// since loads complete while later instructions still read the addresses
// (round-5 crash root cause).
__device__ inline void load16_frags(const char* a0, uint4 f[16]) {
  const char* a1 = a0 + 4096;
  const char* a2 = a0 + 8192;
  const char* a3 = a0 + 12288;
  asm volatile(
    "global_load_dwordx4 %0, %16, off sc0 sc1\n\t"
    "global_load_dwordx4 %1, %16, off offset:1024 sc0 sc1\n\t"
    "global_load_dwordx4 %2, %16, off offset:2048 sc0 sc1\n\t"
    "global_load_dwordx4 %3, %16, off offset:3072 sc0 sc1\n\t"
    "global_load_dwordx4 %4, %17, off sc0 sc1\n\t"
    "global_load_dwordx4 %5, %17, off offset:1024 sc0 sc1\n\t"
    "global_load_dwordx4 %6, %17, off offset:2048 sc0 sc1\n\t"
    "global_load_dwordx4 %7, %17, off offset:3072 sc0 sc1\n\t"
    "global_load_dwordx4 %8, %18, off sc0 sc1\n\t"
    "global_load_dwordx4 %9, %18, off offset:1024 sc0 sc1\n\t"
    "global_load_dwordx4 %10, %18, off offset:2048 sc0 sc1\n\t"
    "global_load_dwordx4 %11, %18, off offset:3072 sc0 sc1\n\t"
    "global_load_dwordx4 %12, %19, off sc0 sc1\n\t"
    "global_load_dwordx4 %13, %19, off offset:1024 sc0 sc1\n\t"
    "global_load_dwordx4 %14, %19, off offset:2048 sc0 sc1\n\t"
    "global_load_dwordx4 %15, %19, off offset:3072 sc0 sc1\n\t"
    "s_waitcnt vmcnt(0)"
    : "=&v"(f[0]), "=&v"(f[1]), "=&v"(f[2]), "=&v"(f[3]),
      "=&v"(f[4]), "=&v"(f[5]), "=&v"(f[6]), "=&v"(f[7]),
      "=&v"(f[8]), "=&v"(f[9]), "=&v"(f[10]), "=&v"(f[11]),
      "=&v"(f[12]), "=&v"(f[13]), "=&v"(f[14]), "=&v"(f[15])
    : "v"(a0), "v"(a1), "v"(a2), "v"(a3));
}

// ---------------- init: zero h double-buffers + barrier counters ----------------
__global__ void init_zero_k(uint4* __restrict__ z, int n4, u32* __restrict__ cnt) {
  const int i = blockIdx.x * blockDim.x + threadIdx.x;
  if (i < n4)  z[i] = make_uint4(0u, 0u, 0u, 0u);
  if (i < 256) cnt[i] = 0u;
}

// ---------------- phase A: G1 = emb[x] @ Wih1^T (bf16 MFMA), relayout epilogue ----
// Relayout staging LDS (ltile) OVERLAYS lA/lB (acc lives in regs by then).
__global__ __launch_bounds__(256) void gemm_g1(
    const int* __restrict__ x, const float* __restrict__ emb,
    const float* __restrict__ Wih, u16* __restrict__ G1)
{
  __shared__ __align__(16) u16 lsbuf[2 * 128 * 72];   // 36864 B, aliased below
  __shared__ int tokoff[128];
  u16* lA = lsbuf;               // [128*72]
  u16* lB = lsbuf + 128 * 72;    // [128*72]
  u16* ltile = lsbuf;            // [128*136] (17408 u16 <= 18432), reused after K-loop

  const int tid = threadIdx.x;
  const int ntb = blockIdx.x & 31;     // N tile (gate rows)
  const int mtb = blockIdx.x >> 5;     // M tile (time*batch rows)

  if (tid < 128) {
    const int n = mtb * 128 + tid;
    tokoff[tid] = x[(n & 31) * 512 + (n >> 5)];   // x[b][t], b=n&31, t=n>>5
  }
  __syncthreads();

  const int lane = tid & 63;
  const int wv = tid >> 6;
  const int wm = (wv & 1) * 64;
  const int wn = (wv >> 1) * 64;

  const f32x4 zero = {0.f, 0.f, 0.f, 0.f};
  f32x4 acc[4][4];
#pragma unroll
  for (int i = 0; i < 4; ++i)
#pragma unroll
    for (int j = 0; j < 4; ++j) acc[i][j] = zero;

  const int rowS = tid >> 1;
  const int kh = (tid & 1) * 32;
  const size_t embrow = (size_t)tokoff[rowS] * 1024;
  const size_t wihrow = (size_t)(ntb * 128 + rowS) * 1024;

  for (int kk = 0; kk < 1024; kk += 64) {
    __syncthreads();
    {
      const float4* sa = (const float4*)(emb + embrow + kk + kh);
      const float4* sb = (const float4*)(Wih + wihrow + kk + kh);
#pragma unroll
      for (int v = 0; v < 4; ++v) {
        *(short8*)&lA[rowS * 72 + kh + v * 8] = pack_bf16x8(sa[2 * v], sa[2 * v + 1]);
        *(short8*)&lB[rowS * 72 + kh + v * 8] = pack_bf16x8(sb[2 * v], sb[2 * v + 1]);
      }
    }
    __syncthreads();
#pragma unroll
    for (int ks = 0; ks < 2; ++ks) {
      short8 aF[4], bF[4];
#pragma unroll
      for (int i = 0; i < 4; ++i)
        aF[i] = *(const short8*)&lA[(wm + i * 16 + (lane & 15)) * 72 + ks * 32 + (lane >> 4) * 8];
#pragma unroll
      for (int i = 0; i < 4; ++i)
        bF[i] = *(const short8*)&lB[(wn + i * 16 + (lane & 15)) * 72 + ks * 32 + (lane >> 4) * 8];
#pragma unroll
      for (int i = 0; i < 4; ++i)
#pragma unroll
        for (int j = 0; j < 4; ++j)
          acc[i][j] = __builtin_amdgcn_mfma_f32_16x16x32_bf16(aF[i], bF[j], acc[i][j], 0, 0, 0);
    }
  }
  __syncthreads();   // all waves done reading lA/lB before ltile overlay writes

  // stage the 128x128 bf16 tile in LDS, then store in [t][w][gate][u][b] layout
#pragma unroll
  for (int i = 0; i < 4; ++i)
#pragma unroll
    for (int j = 0; j < 4; ++j)
#pragma unroll
      for (int r = 0; r < 4; ++r)
        ltile[(wm + i * 16 + (lane >> 4) * 4 + r) * 136 + wn + j * 16 + (lane & 15)] =
            f2bf(acc[i][j][r]);
  __syncthreads();

  const int gate = ntb >> 3;
  const int w0 = (ntb & 7) * 16;
  const int chunkid = tid >> 2;      // 0..63  (tloc 0..3 x wloc 0..15)
  const int part = tid & 3;          // quarter of a 512-B chunk
  const int tloc = chunkid >> 4;
  const int wloc = chunkid & 15;
  const size_t base =
      ((size_t)((mtb * 4 + tloc) * 128 + w0 + wloc) * 4 + gate) * 256;
#pragma unroll
  for (int m = 0; m < 8; ++m) {
    const int idx = part * 64 + m * 8;     // u*32 + b0, b0 in {0,8,16,24}
    const int u = idx >> 5;
    const int b0 = idx & 31;
    union { u16 h[8]; uint4 q; } t;
#pragma unroll
    for (int k = 0; k < 8; ++k)
      t.h[k] = ltile[(tloc * 32 + b0 + k) * 136 + wloc * 8 + u];
    *(uint4*)(G1 + base + idx) = t.q;
  }
}

// ---------------- grid barrier: relaxed counters (round-3 proven) ----------------
__device__ inline void gbar(u32* cnt, u32 target) {
  asm volatile("" ::: "memory");
  if (threadIdx.x == 0)
    __hip_atomic_fetch_add(cnt + ((blockIdx.x & 7) << 5), 1u,
                           __ATOMIC_RELAXED, __HIP_MEMORY_SCOPE_AGENT);
  if (threadIdx.x < 64) {
    int guard = 0;
    for (;;) {
      u32 v = 0;
      if (threadIdx.x < 8)
        v = __hip_atomic_load(cnt + (threadIdx.x << 5),
                              __ATOMIC_RELAXED, __HIP_MEMORY_SCOPE_AGENT);
      v += __shfl_xor(v, 1);
      v += __shfl_xor(v, 2);
      v += __shfl_xor(v, 4);
      v = __shfl(v, 0);
      if (v >= target) break;
      if (++guard > (1 << 20)) break;   // hang insurance
      __builtin_amdgcn_s_sleep(1);
    }
  }
  __syncthreads();
  asm volatile("" ::: "memory");
}

// ---------------- persistent fused 2-layer LSTM recurrence (round-3 skeleton) ----
// 256 blocks x 256 threads (1 block/CU). Block w of a layer owns units w*8..w*8+7.
// Wave split: L0: wave wv does K in [wv*256, +256) of Whh1 (16 frags = 64 VGPR).
//             L1: waves 0,1 = K-halves of Wih2 (A=h1[t2]); waves 2,3 = K-halves of
//                 Whh2 (A=h2[t2-1]) (32 frags = 128 VGPR).
// h buffers: chunk(kb,b) = kb*32+b holds h[b][kb*8..kb*8+7] bf16 (16 B).
__global__ __launch_bounds__(256, 1) void lstm_recur(
    const float* __restrict__ Wih_all, const float* __restrict__ Whh_all,
    const float* __restrict__ bias_all, const u16* __restrict__ G1,
    u64* __restrict__ h1buf, u64* __restrict__ h2buf,
    float* __restrict__ h2f, u32* __restrict__ cnt)
{
  __shared__ float gp[4][32][33];                // per-wave partial gates (16.9 KB)
  __shared__ __align__(16) u16 hpack[32 * 8];    // [b][u] bf16 staging

  const int tid = threadIdx.x;
  const int lane = tid & 63;
  const int wv = tid >> 6;
  const int bid = blockIdx.x;
  const int layer = bid >> 7;
  const int w = bid & 127;      // owns hidden units j = w*8 .. w*8+7

  const int pu = tid & 7;       // pointwise: unit
  const int pb = tid >> 3;      // pointwise: batch
  float creg = 0.f;             // cell state lives in a register
  float bs0, bs1, bs2, bs3;
  {
    const float* bb = bias_all + layer * 4096 + w * 8 + pu;
    bs0 = bb[0]; bs1 = bb[1024]; bs2 = bb[2048]; bs3 = bb[3072];
  }

  // ---- per-wave GEMM slice & weight B-fragments (VGPR-resident) ----
  const int K0w = (layer == 0) ? (wv * 256) : ((wv & 1) * 512);
  const int nA = lane & 31;                  // gate col within block
  const int kpart = (lane >> 5) * 8;         // k sub-offset inside a 16-k MFMA step
  const size_t wrow = (size_t)((nA >> 3) * 1024 + w * 8 + (nA & 7)) * 1024;
  const float* Wsrc = (layer == 0) ? Whh_all
                    : ((wv < 2) ? (Wih_all + 4194304) : (Whh_all + 4194304));

  short8 bw[32];   // L0 uses [0..16), L1 uses all 32
#pragma unroll
  for (int ks = 0; ks < 16; ++ks) {
    const float* p = Wsrc + wrow + (K0w + ks * 16 + kpart);
    bw[ks] = pack_bf16x8(((const float4*)p)[0], ((const float4*)p)[1]);
  }
  if (layer == 1) {
#pragma unroll
    for (int ks = 16; ks < 32; ++ks) {
      const float* p = Wsrc + wrow + (K0w + ks * 16 + kpart);
      bw[ks] = pack_bf16x8(((const float4*)p)[0], ((const float4*)p)[1]);
    }
  }

  // per-lane A byte offset within a parity buffer (frag stride = 1024 B)
  const int aoff = (((K0w >> 3) + (lane >> 5)) * 32 + (lane & 31)) * 16;

  // prefetch step-0 input-projection gates (layer 0), new G1 slab layout
  float g0 = 0.f, g1v = 0.f, g2 = 0.f, g3 = 0.f;
  if (layer == 0) {
    const u16* gpt = G1 + (size_t)w * 1024 + pu * 32 + pb;   // t=0
    g0 = bf2f(gpt[0]); g1v = bf2f(gpt[256]); g2 = bf2f(gpt[512]); g3 = bf2f(gpt[768]);
  }

  for (int s = 0; s <= 512; ++s) {
    const bool active = (layer == 0) ? (s < 512) : (s >= 1);
    if (active) {
      const char* hb;
      if (layer == 0) {
        hb = (const char*)(h1buf + (size_t)((s - 1) & 1) * 8192);
      } else {
        const int t2 = s - 1;
        hb = (wv < 2) ? (const char*)(h1buf + (size_t)(t2 & 1) * 8192)
                      : (const char*)(h2buf + (size_t)((t2 - 1) & 1) * 8192);
      }
      const char* a0 = hb + aoff;
      f32x16 acc = {0.f,0.f,0.f,0.f,0.f,0.f,0.f,0.f,0.f,0.f,0.f,0.f,0.f,0.f,0.f,0.f};
      uint4 f[16];
      load16_frags(a0, f);
      if (layer == 0) {
#pragma unroll
        for (int i = 0; i < 16; ++i)
          acc = mfma32(__builtin_bit_cast(short8, f[i]), bw[i], acc);
      } else {
#pragma unroll
        for (int i = 0; i < 16; ++i)
          acc = mfma32(__builtin_bit_cast(short8, f[i]), bw[i], acc);
        load16_frags(a0 + 16384, f);
#pragma unroll
        for (int i = 0; i < 16; ++i)
          acc = mfma32(__builtin_bit_cast(short8, f[i]), bw[16 + i], acc);
      }
      // 32x32 C/D layout: col = lane&31, row = (r&3) + 8*(r>>2) + 4*(lane>>5)
#pragma unroll
      for (int r = 0; r < 16; ++r)
        gp[wv][(r & 3) + 8 * (r >> 2) + 4 * (lane >> 5)][lane & 31] = acc[r];
    }
    __syncthreads();
    if (active) {
      float gi = bs0 + g0, gf = bs1 + g1v, gg = bs2 + g2, go = bs3 + g3;
#pragma unroll
      for (int q = 0; q < 4; ++q) {
        gi += gp[q][pb][pu];
        gf += gp[q][pb][8 + pu];
        gg += gp[q][pb][16 + pu];
        go += gp[q][pb][24 + pu];
      }
      creg = sigf(gf) * creg + sigf(gi) * tanhfast(gg);
      const float hval = sigf(go) * tanhfast(creg);
      hpack[pb * 8 + pu] = f2bf(hval);
      if (layer == 1 && s == 512) h2f[pb * 1024 + w * 8 + pu] = hval;
    }
    __syncthreads();
    if (active && s < 512 && tid < 32) {
      const u64* hp = (const u64*)(hpack + tid * 8);
      const u64 lo = hp[0], hi = hp[1];
      u64* dst = (layer == 0) ? (h1buf + (size_t)(s & 1) * 8192)
                              : (h2buf + (size_t)((s - 1) & 1) * 8192);
      const int chunk = w * 32 + tid;           // chunk(kb=w, b=tid)
      __hip_atomic_store(dst + chunk * 2,     lo, __ATOMIC_RELAXED, __HIP_MEMORY_SCOPE_AGENT);
      __hip_atomic_store(dst + chunk * 2 + 1, hi, __ATOMIC_RELAXED, __HIP_MEMORY_SCOPE_AGENT);
    }
    // prefetch next step's G1 gates (layer 0) — overlaps the barrier poll
    if (layer == 0 && s + 1 < 512) {
      const u16* gpt = G1 + ((size_t)(s + 1) * 128 + w) * 1024 + pu * 32 + pb;
      g0 = bf2f(gpt[0]); g1v = bf2f(gpt[256]); g2 = bf2f(gpt[512]); g3 = bf2f(gpt[768]);
    }
    if (s < 512) {
      // wave 0 drains its h stores to LLC before thread 0 posts
      if (wv == 0) __builtin_amdgcn_s_waitcnt(0);
      gbar(cnt, 256u * (u32)(s + 1));
    }
  }
}

// ---------------- epilogue: logits, log-softmax, NLL ----------------
__global__ __launch_bounds__(256) void epilogue_k(
    const float* __restrict__ h2f, const float* __restrict__ fcW,
    const float* __restrict__ fcb, const int* __restrict__ labels,
    float* __restrict__ out)
{
  __shared__ float slog[160];
  __shared__ float snll[32];
  const int tid = threadIdx.x;
  const int lane = tid & 63;
  const int wv = tid >> 6;
  for (int d = wv * 40; d < (wv + 1) * 40; ++d) {
    const int b = d / 5, l = d - b * 5;
    const float* hr = h2f + b * 1024 + lane * 16;
    const float* wr = fcW + l * 1024 + lane * 16;
    float sacc = 0.f;
#pragma unroll
    for (int i = 0; i < 16; ++i) sacc += hr[i] * wr[i];
#pragma unroll
    for (int off = 32; off > 0; off >>= 1) sacc += __shfl_down(sacc, off);
    if (lane == 0) slog[d] = sacc + fcb[l];
  }
  __syncthreads();
  if (tid < 32) {
    const int b = tid;
    float m = slog[b * 5];
    for (int l = 1; l < 5; ++l) m = fmaxf(m, slog[b * 5 + l]);
    float se = 0.f;
    for (int l = 0; l < 5; ++l) se += __expf(slog[b * 5 + l] - m);
    const float lse = m + __logf(se);
    for (int l = 0; l < 5; ++l) out[1 + b * 5 + l] = slog[b * 5 + l];
    snll[b] = lse - slog[b * 5 + labels[b]];
  }
  __syncthreads();
  if (tid == 0) {
    float a = 0.f;
    for (int b = 0; b < 32; ++b) a += snll[b];
    out[0] = a * (1.f / 32.f);
  }
}

extern "C" void kernel_launch(void* const* d_in, const int* in_sizes, int n_in,
                              void* d_out, int out_size, void* d_ws, size_t ws_size,
                              hipStream_t stream)
{
  const int*   x      = (const int*)  d_in[0];
  const int*   labels = (const int*)  d_in[1];
  const float* emb    = (const float*)d_in[2];
  const float* W_ih   = (const float*)d_in[3];
  const float* W_hh   = (const float*)d_in[4];
  const float* bias   = (const float*)d_in[5];
  const float* fcW    = (const float*)d_in[6];
  const float* fcb    = (const float*)d_in[7];
  float* out = (float*)d_out;

  char* ws = (char*)d_ws;
  u16* G1    = (u16*)ws;
  u64* h1buf = (u64*)(ws + OFF_H1);
  u64* h2buf = (u64*)(ws + OFF_H2);
  float* h2f = (float*)(ws + OFF_H2F);
  u32* cnt   = (u32*)(ws + OFF_CNT);

  // zero h double-buffers (262144 B = 16384 uint4) + barrier counters
  init_zero_k<<<dim3(64), dim3(256), 0, stream>>>((uint4*)(ws + OFF_H1), 16384, cnt);
  // phase A: all input projections for layer 1 (relayout epilogue)
  gemm_g1<<<dim3(4096), dim3(256), 0, stream>>>(x, emb, W_ih, G1);
  // persistent fused recurrence (1 block/CU, 256 threads)
  lstm_recur<<<dim3(256), dim3(256), 0, stream>>>(W_ih, W_hh, bias, G1, h1buf, h2buf, h2f, cnt);
  // loss + logits
  epilogue_k<<<dim3(1), dim3(256), 0, stream>>>(h2f, fcW, fcb, labels, out);
}

// Round 7
// 3452.022 us; speedup vs baseline: 7.4857x; 1.1306x over previous
//
#include <hip/hip_runtime.h>

typedef unsigned short u16;
typedef unsigned int   u32;
typedef unsigned long long u64;
typedef __attribute__((ext_vector_type(8))) short short8;    // 8 x bf16 operand (4 VGPRs)
typedef __attribute__((ext_vector_type(4))) float f32x4;     // 16x16 MFMA accumulator
typedef __attribute__((ext_vector_type(16))) float f32x16;   // 32x32 MFMA accumulator

// ---------------- workspace layout (bytes) ----------------
// G1    : [512 t][128 w][4 gate][8 u][32 b] bf16 = 134217728  (block-local 2 KB slabs)
// h1ring: 4 ring buffers, 32x32-A-frag layout (chunk = kb*32+b, 16 B), 64 KiB each
// h2buf : 2 parity buffers, same layout
// h2f   : final h2 [32][1024] fp32
// cnt   : cnt0 = 8 counters at u32 idx i*32 (L0), cnt1 = 8 at 1024+i*32 (L1); 8 KiB
#define OFF_H1   134217728ull
#define OFF_H2   (OFF_H1 + 262144ull)
#define OFF_H2F  (OFF_H2 + 131072ull)
#define OFF_CNT  (OFF_H2F + 131072ull)

__device__ inline u16 f2bf(float f) {                  // fp32 -> bf16 RNE
  u32 x = __float_as_uint(f);
  x += 0x7fffu + ((x >> 16) & 1u);
  return (u16)(x >> 16);
}
__device__ inline float bf2f(u16 u) { return __uint_as_float(((u32)u) << 16); }

__device__ inline short8 pack_bf16x8(float4 a, float4 b) {
  short8 r;
  r[0] = (short)f2bf(a.x); r[1] = (short)f2bf(a.y); r[2] = (short)f2bf(a.z); r[3] = (short)f2bf(a.w);
  r[4] = (short)f2bf(b.x); r[5] = (short)f2bf(b.y); r[6] = (short)f2bf(b.z); r[7] = (short)f2bf(b.w);
  return r;
}

__device__ inline f32x16 mfma32(short8 a, short8 b, f32x16 c) {
  return __builtin_amdgcn_mfma_f32_32x32x16_bf16(a, b, c, 0, 0, 0);
}

__device__ inline float sigf(float x) { return 1.f / (1.f + __expf(-x)); }
__device__ inline float tanhfast(float x) {
  x = fminf(15.f, fmaxf(-15.f, x));
  float e = __expf(2.f * x);
  return (e - 1.f) / (e + 1.f);
}

// 8 coherent (LLC-direct) 16-B loads, pipelined, drained inside the asm.
// "=&v" early-clobber: outputs must not alias address inputs (round-5 crash).
__device__ inline void load8_frags(const char* a0, uint4 f[8]) {
  const char* a1 = a0 + 4096;
  asm volatile(
    "global_load_dwordx4 %0, %8, off sc0 sc1\n\t"
    "global_load_dwordx4 %1, %8, off offset:1024 sc0 sc1\n\t"
    "global_load_dwordx4 %2, %8, off offset:2048 sc0 sc1\n\t"
    "global_load_dwordx4 %3, %8, off offset:3072 sc0 sc1\n\t"
    "global_load_dwordx4 %4, %9, off sc0 sc1\n\t"
    "global_load_dwordx4 %5, %9, off offset:1024 sc0 sc1\n\t"
    "global_load_dwordx4 %6, %9, off offset:2048 sc0 sc1\n\t"
    "global_load_dwordx4 %7, %9, off offset:3072 sc0 sc1\n\t"
    "s_waitcnt vmcnt(0)"
    : "=&v"(f[0]), "=&v"(f[1]), "=&v"(f[2]), "=&v"(f[3]),
      "=&v"(f[4]), "=&v"(f[5]), "=&v"(f[6]), "=&v"(f[7])
    : "v"(a0), "v"(a1));
}

// 16 loads from two independent streams (h1 + h2) in ONE flight group: 1 LLC RT.
__device__ inline void load16_dual(const char* aI, const char* aH,
                                   uint4 fI[8], uint4 fH[8]) {
  const char* aI1 = aI + 4096;
  const char* aH1 = aH + 4096;
  asm volatile(
    "global_load_dwordx4 %0, %16, off sc0 sc1\n\t"
    "global_load_dwordx4 %1, %16, off offset:1024 sc0 sc1\n\t"
    "global_load_dwordx4 %2, %16, off offset:2048 sc0 sc1\n\t"
    "global_load_dwordx4 %3, %16, off offset:3072 sc0 sc1\n\t"
    "global_load_dwordx4 %4, %17, off sc0 sc1\n\t"
    "global_load_dwordx4 %5, %17, off offset:1024 sc0 sc1\n\t"
    "global_load_dwordx4 %6, %17, off offset:2048 sc0 sc1\n\t"
    "global_load_dwordx4 %7, %17, off offset:3072 sc0 sc1\n\t"
    "global_load_dwordx4 %8, %18, off sc0 sc1\n\t"
    "global_load_dwordx4 %9, %18, off offset:1024 sc0 sc1\n\t"
    "global_load_dwordx4 %10, %18, off offset:2048 sc0 sc1\n\t"
    "global_load_dwordx4 %11, %18, off offset:3072 sc0 sc1\n\t"
    "global_load_dwordx4 %12, %19, off sc0 sc1\n\t"
    "global_load_dwordx4 %13, %19, off offset:1024 sc0 sc1\n\t"
    "global_load_dwordx4 %14, %19, off offset:2048 sc0 sc1\n\t"
    "global_load_dwordx4 %15, %19, off offset:3072 sc0 sc1\n\t"
    "s_waitcnt vmcnt(0)"
    : "=&v"(fI[0]), "=&v"(fI[1]), "=&v"(fI[2]), "=&v"(fI[3]),
      "=&v"(fI[4]), "=&v"(fI[5]), "=&v"(fI[6]), "=&v"(fI[7]),
      "=&v"(fH[0]), "=&v"(fH[1]), "=&v"(fH[2]), "=&v"(fH[3]),
      "=&v"(fH[4]), "=&v"(fH[5]), "=&v"(fH[6]), "=&v"(fH[7])
    : "v"(aI), "v"(aI1), "v"(aH), "v"(aH1));
}

// ---------------- init: zero h ring+h2 buffers + barrier counters ----------------
__global__ void init_zero_k(uint4* __restrict__ z, int n4, u32* __restrict__ cnt) {
  const int i = blockIdx.x * blockDim.x + threadIdx.x;
  if (i < n4)   z[i] = make_uint4(0u, 0u, 0u, 0u);
  if (i < 2048) cnt[i] = 0u;
}

// ---------------- phase A: G1 = emb[x] @ Wih1^T (bf16 MFMA), relayout epilogue ----
__global__ __launch_bounds__(256) void gemm_g1(
    const int* __restrict__ x, const float* __restrict__ emb,
    const float* __restrict__ Wih, u16* __restrict__ G1)
{
  __shared__ __align__(16) u16 lsbuf[2 * 128 * 72];   // 36864 B, aliased below
  __shared__ int tokoff[128];
  u16* lA = lsbuf;               // [128*72]
  u16* lB = lsbuf + 128 * 72;    // [128*72]
  u16* ltile = lsbuf;            // [128*136], reused after K-loop

  const int tid = threadIdx.x;
  const int ntb = blockIdx.x & 31;     // N tile (gate rows)
  const int mtb = blockIdx.x >> 5;     // M tile (time*batch rows)

  if (tid < 128) {
    const int n = mtb * 128 + tid;
    tokoff[tid] = x[(n & 31) * 512 + (n >> 5)];   // x[b][t], b=n&31, t=n>>5
  }
  __syncthreads();

  const int lane = tid & 63;
  const int wv = tid >> 6;
  const int wm = (wv & 1) * 64;
  const int wn = (wv >> 1) * 64;

  const f32x4 zero = {0.f, 0.f, 0.f, 0.f};
  f32x4 acc[4][4];
#pragma unroll
  for (int i = 0; i < 4; ++i)
#pragma unroll
    for (int j = 0; j < 4; ++j) acc[i][j] = zero;

  const int rowS = tid >> 1;
  const int kh = (tid & 1) * 32;
  const size_t embrow = (size_t)tokoff[rowS] * 1024;
  const size_t wihrow = (size_t)(ntb * 128 + rowS) * 1024;

  for (int kk = 0; kk < 1024; kk += 64) {
    __syncthreads();
    {
      const float4* sa = (const float4*)(emb + embrow + kk + kh);
      const float4* sb = (const float4*)(Wih + wihrow + kk + kh);
#pragma unroll
      for (int v = 0; v < 4; ++v) {
        *(short8*)&lA[rowS * 72 + kh + v * 8] = pack_bf16x8(sa[2 * v], sa[2 * v + 1]);
        *(short8*)&lB[rowS * 72 + kh + v * 8] = pack_bf16x8(sb[2 * v], sb[2 * v + 1]);
      }
    }
    __syncthreads();
#pragma unroll
    for (int ks = 0; ks < 2; ++ks) {
      short8 aF[4], bF[4];
#pragma unroll
      for (int i = 0; i < 4; ++i)
        aF[i] = *(const short8*)&lA[(wm + i * 16 + (lane & 15)) * 72 + ks * 32 + (lane >> 4) * 8];
#pragma unroll
      for (int i = 0; i < 4; ++i)
        bF[i] = *(const short8*)&lB[(wn + i * 16 + (lane & 15)) * 72 + ks * 32 + (lane >> 4) * 8];
#pragma unroll
      for (int i = 0; i < 4; ++i)
#pragma unroll
        for (int j = 0; j < 4; ++j)
          acc[i][j] = __builtin_amdgcn_mfma_f32_16x16x32_bf16(aF[i], bF[j], acc[i][j], 0, 0, 0);
    }
  }
  __syncthreads();   // done reading lA/lB before ltile overlay writes

#pragma unroll
  for (int i = 0; i < 4; ++i)
#pragma unroll
    for (int j = 0; j < 4; ++j)
#pragma unroll
      for (int r = 0; r < 4; ++r)
        ltile[(wm + i * 16 + (lane >> 4) * 4 + r) * 136 + wn + j * 16 + (lane & 15)] =
            f2bf(acc[i][j][r]);
  __syncthreads();

  const int gate = ntb >> 3;
  const int w0 = (ntb & 7) * 16;
  const int chunkid = tid >> 2;      // 0..63  (tloc 0..3 x wloc 0..15)
  const int part = tid & 3;          // quarter of a 512-B chunk
  const int tloc = chunkid >> 4;
  const int wloc = chunkid & 15;
  const size_t base =
      ((size_t)((mtb * 4 + tloc) * 128 + w0 + wloc) * 4 + gate) * 256;
#pragma unroll
  for (int m = 0; m < 8; ++m) {
    const int idx = part * 64 + m * 8;     // u*32 + b0
    const int u = idx >> 5;
    const int b0 = idx & 31;
    union { u16 h[8]; uint4 q; } t;
#pragma unroll
    for (int k = 0; k < 8; ++k)
      t.h[k] = ltile[(tloc * 32 + b0 + k) * 136 + wloc * 8 + u];
    *(uint4*)(G1 + base + idx) = t.q;
  }
}

// ---------------- split grid wait: sum(cnt0) >= t0 && sum(cnt1) >= t1 ----------------
__device__ inline void gwait(u32* cnt, int t0, int t1) {
  if (threadIdx.x < 64 && (t0 > 0 || t1 > 0)) {
    int guard = 0;
    for (;;) {
      int v = 0;
      if (threadIdx.x < 8)
        v = (int)__hip_atomic_load(cnt + threadIdx.x * 32,
                                   __ATOMIC_RELAXED, __HIP_MEMORY_SCOPE_AGENT);
      else if (threadIdx.x < 16)
        v = (int)__hip_atomic_load(cnt + 1024 + (threadIdx.x - 8) * 32,
                                   __ATOMIC_RELAXED, __HIP_MEMORY_SCOPE_AGENT);
      v += __shfl_xor(v, 1);
      v += __shfl_xor(v, 2);
      v += __shfl_xor(v, 4);
      const int s0 = __shfl(v, 0);
      const int s1 = __shfl(v, 8);
      if (s0 >= t0 && s1 >= t1) break;
      if (++guard > (1 << 20)) break;   // hang insurance
      __builtin_amdgcn_s_sleep(1);
    }
  }
  __syncthreads();
  asm volatile("" ::: "memory");
}

// ---------------- persistent fused 2-layer LSTM, decoupled layer pipelines ----------
// 256 blocks x 512 threads (1 block/CU, 8 waves, (512,2) -> 256-VGPR cap).
// Block w of layer l owns hidden units w*8..w*8+7. 8 waves split K: wave wv does
// K in [wv*128,+128) of every matrix it touches.
//   L0: Whh1 slice in VGPR (8 frags). Reads h1ring[(s-1)%4], writes h1ring[s%4].
//       Waits: cnt0 >= 128*s (h1[s-1] ready), cnt1 >= 128*(s-3) (ring overwrite guard).
//   L1: Wih2 + Whh2 slices in VGPR (8+8 frags). Reads h1ring[s%4] + h2[(s-1)&1]
//       in ONE 16-load flight group; writes h2[s&1].
//       Waits: cnt0 >= 128*(s+1) (h1[s] ready), cnt1 >= 128*s (own prior step).
__global__ __launch_bounds__(512, 2) void lstm_recur(
    const float* __restrict__ Wih_all, const float* __restrict__ Whh_all,
    const float* __restrict__ bias_all, const u16* __restrict__ G1,
    u64* __restrict__ h1ring, u64* __restrict__ h2buf,
    float* __restrict__ h2f, u32* __restrict__ cnt)
{
  __shared__ float gp[8][32][33];                // per-wave partial gates (33.8 KB)
  __shared__ __align__(16) u16 hpack[32 * 8];    // [b][u] bf16 staging

  const int tid = threadIdx.x;
  const int lane = tid & 63;
  const int wv = tid >> 6;          // 0..7
  const int bid = blockIdx.x;
  const int layer = bid >> 7;
  const int w = bid & 127;

  const int pu = (tid >> 5) & 7;    // pointwise: unit
  const int pb = tid & 31;          // pointwise: batch
  const bool pw_act = tid < 256;
  float creg = 0.f;
  float bs0 = 0.f, bs1 = 0.f, bs2 = 0.f, bs3 = 0.f;
  if (pw_act) {
    const float* bb = bias_all + layer * 4096 + w * 8 + pu;
    bs0 = bb[0]; bs1 = bb[1024]; bs2 = bb[2048]; bs3 = bb[3072];
  }

  // ---- weight B-fragments, VGPR-resident ----
  const int nA = lane & 31;
  const int kpart = (lane >> 5) * 8;
  const size_t wrow = (size_t)((nA >> 3) * 1024 + w * 8 + (nA & 7)) * 1024;
  const int K0 = wv * 128;
  short8 bw0[8], bw1[8];   // L0: bw0=Whh1 (bw1 unused); L1: bw0=Wih2, bw1=Whh2
  {
    const float* s0 = (layer == 0) ? Whh_all : (Wih_all + 4194304);
#pragma unroll
    for (int ks = 0; ks < 8; ++ks) {
      const float* p = s0 + wrow + (K0 + ks * 16 + kpart);
      bw0[ks] = pack_bf16x8(((const float4*)p)[0], ((const float4*)p)[1]);
    }
    if (layer == 1) {
      const float* s1 = Whh_all + 4194304;
#pragma unroll
      for (int ks = 0; ks < 8; ++ks) {
        const float* p = s1 + wrow + (K0 + ks * 16 + kpart);
        bw1[ks] = pack_bf16x8(((const float4*)p)[0], ((const float4*)p)[1]);
      }
    }
  }

  // per-lane A byte offset within one 64 KiB buffer
  const int aoff = ((wv * 16 + (lane >> 5)) * 32 + (lane & 31)) * 16;

  // prefetch step-0 input-projection gates (layer 0)
  float g0 = 0.f, g1v = 0.f, g2 = 0.f, g3 = 0.f;
  if (layer == 0 && pw_act) {
    const u16* gpt = G1 + (size_t)w * 1024 + pu * 32 + pb;   // t=0
    g0 = bf2f(gpt[0]); g1v = bf2f(gpt[256]); g2 = bf2f(gpt[512]); g3 = bf2f(gpt[768]);
  }

  for (int s = 0; s < 512; ++s) {
    if (layer == 0) gwait(cnt, 128 * s, 128 * (s - 3));
    else            gwait(cnt, 128 * (s + 1), 128 * s);

    f32x16 accA = {0.f,0.f,0.f,0.f,0.f,0.f,0.f,0.f,0.f,0.f,0.f,0.f,0.f,0.f,0.f,0.f};
    if (layer == 0) {
      const char* a0 = (const char*)h1ring + (size_t)((s + 3) & 3) * 65536 + aoff;
      uint4 f[8];
      load8_frags(a0, f);
#pragma unroll
      for (int i = 0; i < 8; ++i)
        accA = mfma32(__builtin_bit_cast(short8, f[i]), bw0[i], accA);
    } else {
      const char* aI = (const char*)h1ring + (size_t)(s & 3) * 65536 + aoff;
      const char* aH = (const char*)h2buf + (size_t)((s + 1) & 1) * 65536 + aoff;
      uint4 fI[8], fH[8];
      load16_dual(aI, aH, fI, fH);
      f32x16 accB = {0.f,0.f,0.f,0.f,0.f,0.f,0.f,0.f,0.f,0.f,0.f,0.f,0.f,0.f,0.f,0.f};
#pragma unroll
      for (int i = 0; i < 8; ++i)
        accA = mfma32(__builtin_bit_cast(short8, fI[i]), bw0[i], accA);
#pragma unroll
      for (int i = 0; i < 8; ++i)
        accB = mfma32(__builtin_bit_cast(short8, fH[i]), bw1[i], accB);
      accA += accB;
    }
    // 32x32 C/D layout: col = lane&31, row = (r&3) + 8*(r>>2) + 4*(lane>>5)
#pragma unroll
    for (int r = 0; r < 16; ++r)
      gp[wv][(r & 3) + 8 * (r >> 2) + 4 * (lane >> 5)][lane & 31] = accA[r];
    __syncthreads();
    if (pw_act) {
      float gi = bs0 + g0, gf = bs1 + g1v, gg = bs2 + g2, go = bs3 + g3;
#pragma unroll
      for (int q = 0; q < 8; ++q) {
        gi += gp[q][pb][pu];
        gf += gp[q][pb][8 + pu];
        gg += gp[q][pb][16 + pu];
        go += gp[q][pb][24 + pu];
      }
      creg = sigf(gf) * creg + sigf(gi) * tanhfast(gg);
      const float hval = sigf(go) * tanhfast(creg);
      hpack[pb * 8 + pu] = f2bf(hval);
      if (layer == 1 && s == 511) h2f[pb * 1024 + w * 8 + pu] = hval;
    }
    __syncthreads();
    if (tid < 32) {
      const u64* hp = (const u64*)(hpack + tid * 8);
      const u64 lo = hp[0], hi = hp[1];
      u64* dst = (layer == 0) ? (h1ring + (size_t)(s & 3) * 8192)
                              : (h2buf + (size_t)(s & 1) * 8192);
      const int chunk = w * 32 + tid;
      __hip_atomic_store(dst + chunk * 2,     lo, __ATOMIC_RELAXED, __HIP_MEMORY_SCOPE_AGENT);
      __hip_atomic_store(dst + chunk * 2 + 1, hi, __ATOMIC_RELAXED, __HIP_MEMORY_SCOPE_AGENT);
    }
    if (wv == 0) {
      __builtin_amdgcn_s_waitcnt(0);    // drain h stores to the coherence point
      if (tid == 0)
        __hip_atomic_fetch_add(cnt + (layer == 0 ? 0 : 1024) + ((bid & 7) << 5), 1u,
                               __ATOMIC_RELAXED, __HIP_MEMORY_SCOPE_AGENT);
    }
    // prefetch next step's G1 gates (layer 0) — after the post so its HBM
    // latency doesn't sit on the signal path
    if (layer == 0 && pw_act && s + 1 < 512) {
      const u16* gpt = G1 + ((size_t)(s + 1) * 128 + w) * 1024 + pu * 32 + pb;
      g0 = bf2f(gpt[0]); g1v = bf2f(gpt[256]); g2 = bf2f(gpt[512]); g3 = bf2f(gpt[768]);
    }
  }
}

// ---------------- epilogue: logits, log-softmax, NLL ----------------
__global__ __launch_bounds__(256) void epilogue_k(
    const float* __restrict__ h2f, const float* __restrict__ fcW,
    const float* __restrict__ fcb, const int* __restrict__ labels,
    float* __restrict__ out)
{
  __shared__ float slog[160];
  __shared__ float snll[32];
  const int tid = threadIdx.x;
  const int lane = tid & 63;
  const int wv = tid >> 6;
  for (int d = wv * 40; d < (wv + 1) * 40; ++d) {
    const int b = d / 5, l = d - b * 5;
    const float* hr = h2f + b * 1024 + lane * 16;
    const float* wr = fcW + l * 1024 + lane * 16;
    float sacc = 0.f;
#pragma unroll
    for (int i = 0; i < 16; ++i) sacc += hr[i] * wr[i];
#pragma unroll
    for (int off = 32; off > 0; off >>= 1) sacc += __shfl_down(sacc, off);
    if (lane == 0) slog[d] = sacc + fcb[l];
  }
  __syncthreads();
  if (tid < 32) {
    const int b = tid;
    float m = slog[b * 5];
    for (int l = 1; l < 5; ++l) m = fmaxf(m, slog[b * 5 + l]);
    float se = 0.f;
    for (int l = 0; l < 5; ++l) se += __expf(slog[b * 5 + l] - m);
    const float lse = m + __logf(se);
    for (int l = 0; l < 5; ++l) out[1 + b * 5 + l] = slog[b * 5 + l];
    snll[b] = lse - slog[b * 5 + labels[b]];
  }
  __syncthreads();
  if (tid == 0) {
    float a = 0.f;
    for (int b = 0; b < 32; ++b) a += snll[b];
    out[0] = a * (1.f / 32.f);
  }
}

extern "C" void kernel_launch(void* const* d_in, const int* in_sizes, int n_in,
                              void* d_out, int out_size, void* d_ws, size_t ws_size,
                              hipStream_t stream)
{
  const int*   x      = (const int*)  d_in[0];
  const int*   labels = (const int*)  d_in[1];
  const float* emb    = (const float*)d_in[2];
  const float* W_ih   = (const float*)d_in[3];
  const float* W_hh   = (const float*)d_in[4];
  const float* bias   = (const float*)d_in[5];
  const float* fcW    = (const float*)d_in[6];
  const float* fcb    = (const float*)d_in[7];
  float* out = (float*)d_out;

  char* ws = (char*)d_ws;
  u16* G1     = (u16*)ws;
  u64* h1ring = (u64*)(ws + OFF_H1);
  u64* h2buf  = (u64*)(ws + OFF_H2);
  float* h2f  = (float*)(ws + OFF_H2F);
  u32* cnt    = (u32*)(ws + OFF_CNT);

  // zero h1 ring + h2 buffers (393216 B = 24576 uint4) + barrier counters
  init_zero_k<<<dim3(96), dim3(256), 0, stream>>>((uint4*)(ws + OFF_H1), 24576, cnt);
  // phase A: all input projections for layer 1 (relayout epilogue)
  gemm_g1<<<dim3(4096), dim3(256), 0, stream>>>(x, emb, W_ih, G1);
  // persistent fused recurrence (1 block/CU, 512 threads, decoupled pipelines)
  lstm_recur<<<dim3(256), dim3(512), 0, stream>>>(W_ih, W_hh, bias, G1, h1ring, h2buf, h2f, cnt);
  // loss + logits
  epilogue_k<<<dim3(1), dim3(256), 0, stream>>>(h2f, fcW, fcb, labels, out);
}